// Round 9
// baseline (808.956 us; speedup 1.0000x reference)
//
#include <hip/hip_runtime.h>

#define CC   256
#define HWS  4096
#define MPAD 4160   // 65*64, rows >= 4097 zero-padded
#define NB   4
#define NTIL 65

typedef __attribute__((ext_vector_type(8))) short   short8;
typedef __attribute__((ext_vector_type(4))) float   floatx4;

static __device__ __forceinline__ short8 ld8(const unsigned short* p) {
  return *(const short8*)p;
}
static __device__ __forceinline__ void st8(unsigned short* p, short8 v) {
  *(short8*)p = v;
}
static __device__ __forceinline__ unsigned short f2b(float x) {
  union { float f; unsigned u; } v; v.f = x;
  unsigned r = v.u + 0x7FFFu + ((v.u >> 16) & 1u);
  return (unsigned short)(r >> 16);
}
static __device__ __forceinline__ float b2f(unsigned short x) {
  union { unsigned u; float f; } v; v.u = ((unsigned)x) << 16;
  return v.f;
}

// ---- merged: St[d][c] = sim[c][d], Vw[d][c] = v_w[d][c] (bf16); colb biases
__global__ void prep_colb(const float* __restrict__ sim, const float* __restrict__ vw,
                          const float* __restrict__ mask,
                          unsigned short* __restrict__ St, unsigned short* __restrict__ Vw,
                          float* __restrict__ colb) {
  int blk = blockIdx.x, tid = threadIdx.x;
  if (blk < CC) {
    int dd = blk, c = tid;
    St[dd*CC + c] = f2b(sim[c*CC + dd]);
    Vw[dd*CC + c] = f2b(vw[dd*CC + c]);
    return;
  }
  int b = blk - CC;
  for (int m = tid; m < MPAD; m += 256) {
    float v;
    if (m < HWS)      v = (mask[b*HWS + m] - 1.0f) * 1e9f;
    else if (m == HWS) v = 0.0f;
    else               v = -3.0e38f;
    colb[b*MPAD + m] = v;
  }
}

// ---- Kt[b][m][d] = bf16(concat[b][d][m]); ALSO writes Kf fragment-major
__global__ void build_kt(const float* __restrict__ img, const float* __restrict__ exe,
                         unsigned short* __restrict__ Kt, unsigned short* __restrict__ Kf) {
  int b = blockIdx.x, mt = blockIdx.y, dt = blockIdx.z;
  int tid = threadIdx.x;
  int m0 = mt*64, d0 = dt*64;
  int w = tid >> 6, lane = tid & 63, lo = lane & 15, hi = lane >> 4;
  unsigned short* kft = Kf + (size_t)(b*NTIL + mt)*16384;
  if (mt == 64) {
    for (int i = 0; i < 16; ++i) {
      int m = m0 + (tid>>6) + i*4;
      int d = d0 + (tid&63);
      unsigned short v = 0;
      if (m == 4096) v = f2b(1.2f * exe[b*CC + d]);
      Kt[((size_t)b*MPAD + m)*CC + d] = v;
    }
#pragma unroll
    for (int ss = 0; ss < 2; ++ss) {
      int s = dt*8 + w*2 + ss;
      int k = s >> 2, t = s & 3;
      unsigned short tmp[8] = {0,0,0,0,0,0,0,0};
      if (t == 0 && lo == 0) {
#pragma unroll
        for (int j = 0; j < 8; ++j)
          tmp[j] = f2b(1.2f * exe[b*CC + k*32 + hi*8 + j]);
      }
      st8(kft + s*512 + lane*8, *(short8*)tmp);
    }
    return;
  }
  __shared__ float tile[64][65];
  for (int i = 0; i < 16; ++i) {
    int dl = (tid>>6) + i*4, ml = tid&63;
    tile[dl][ml] = img[((size_t)b*CC + d0+dl)*HWS + m0+ml];
  }
  __syncthreads();
  for (int i = 0; i < 16; ++i) {
    int ml = (tid>>6) + i*4, dl = tid&63;
    Kt[((size_t)b*MPAD + m0+ml)*CC + d0+dl] = f2b(tile[dl][ml]);
  }
#pragma unroll
  for (int ss = 0; ss < 2; ++ss) {
    int s = dt*8 + w*2 + ss;
    int k = s >> 2, t = s & 3;
    int ml = t*16 + lo;
    int dlb = (k - dt*2)*32 + hi*8;
    unsigned short tmp[8];
#pragma unroll
    for (int j = 0; j < 8; ++j) tmp[j] = f2b(tile[dlb + j][ml]);
    st8(kft + s*512 + lane*8, *(short8*)tmp);
  }
}

// ---- mode 0: Tb[b][n][d] = bf16( sum_c Kt[n][c]*St[d][c] )
// ---- mode 1: Vf fragment-major = bf16( sum_c Kt[m][c]*Vw[d][c] )
__global__ __launch_bounds__(256) void gemm_small(const unsigned short* __restrict__ Kt,
    const unsigned short* __restrict__ Bm, unsigned short* __restrict__ Tout,
    unsigned short* __restrict__ Vf, int mode) {
  int b  = blockIdx.x;
  int by = blockIdx.y;
  int w  = threadIdx.x >> 6;
  int r0 = by*64 + w*16;
  int c0 = blockIdx.z*64;
  int lane = threadIdx.x & 63;
  int lo = lane & 15, hi = lane >> 4;
  __shared__ unsigned short lsh[64][72];
  floatx4 acc[4] = {};
  const unsigned short* arow = Kt + ((size_t)b*MPAD + r0 + lo)*CC + hi*8;
#pragma unroll
  for (int k = 0; k < 8; ++k) {
    short8 af = ld8(arow + k*32);
#pragma unroll
    for (int t = 0; t < 4; ++t) {
      short8 bf = ld8(Bm + (size_t)(c0 + t*16 + lo)*CC + k*32 + hi*8);
      acc[t] = __builtin_amdgcn_mfma_f32_16x16x32_bf16(af, bf, acc[t], 0, 0, 0);
    }
  }
  if (mode == 0) {
#pragma unroll
    for (int t = 0; t < 4; ++t)
#pragma unroll
      for (int r = 0; r < 4; ++r)
        lsh[w*16 + hi*4 + r][t*16 + lo] = f2b(acc[t][r]);
    __syncthreads();
    int tid = threadIdx.x;
    int nl = tid >> 2, seg = tid & 3;
    unsigned short* dst = Tout + ((size_t)b*HWS + by*64 + nl)*CC + c0 + seg*16;
    st8(dst,     ld8(&lsh[nl][seg*16]));
    st8(dst + 8, ld8(&lsh[nl][seg*16 + 8]));
  } else {
#pragma unroll
    for (int t = 0; t < 4; ++t)
#pragma unroll
      for (int r = 0; r < 4; ++r)
        lsh[t*16 + lo][w*16 + hi*4 + r] = f2b(acc[t][r]);
    __syncthreads();
    unsigned short* vfb2 = Vf + (size_t)(b*NTIL + by)*16384;
#pragma unroll
    for (int ss = 0; ss < 2; ++ss) {
      int idx = w*2 + ss;            // [0,8)
      int h = idx >> 2, t4 = idx & 3;
      int s = h*16 + (c0 >> 4) + t4;
      short8 v = ld8(&lsh[t4*16 + (lane & 15)][h*32 + (lane >> 4)*8]);
      st8(vfb2 + s*512 + lane*8, v);
    }
  }
}

// ---- score mimicry of np/BLAS fp32 T-path, sequential FMA everywhere.
__global__ __launch_bounds__(256) void scores_kernel(const float* __restrict__ img,
    const float* __restrict__ sim, const float* __restrict__ exe,
    float* __restrict__ score32) {
  int b = blockIdx.x, n0 = blockIdx.y*32;
  int d = threadIdx.x;
  __shared__ float U[32][257];        // U[nl][c] = img[b, c, n0+nl]
  __shared__ float R[32][257];        // T32[nl][d]
  __shared__ float E[256];
  for (int idx = threadIdx.x; idx < 32*256; idx += 256) {
    int nl = idx & 31, c = idx >> 5;
    U[nl][c] = img[((size_t)b*CC + c)*HWS + n0 + nl];
  }
  E[d] = 1.2f * exe[b*CC + d];
  __syncthreads();
  float acc[32];
#pragma unroll
  for (int nl = 0; nl < 32; ++nl) acc[nl] = 0.f;
  for (int c = 0; c < CC; ++c) {
    float s_cd = sim[c*CC + d];
#pragma unroll
    for (int nl = 0; nl < 32; ++nl) acc[nl] = fmaf(U[nl][c], s_cd, acc[nl]);
  }
#pragma unroll
  for (int nl = 0; nl < 32; ++nl) R[nl][d] = acc[nl];
  __syncthreads();
  if (d < 32) {
    float s = 0.f;
    for (int dd = 0; dd < CC; ++dd) s = fmaf(R[d][dd], E[dd], s);
    score32[b*HWS + n0 + d] = s;
  }
}

// ---- top-150 via exact radix-select on distinct 44-bit keys + bitonic-256 sort.
__global__ __launch_bounds__(64) void select_kernel(const float* __restrict__ scores,
                                                    int* __restrict__ qids) {
  int b = blockIdx.x, lane = threadIdx.x;
  __shared__ float sc[HWS];
  __shared__ unsigned long long kx[HWS];
  __shared__ unsigned long long list[256];
  __shared__ unsigned int hist[256];
  __shared__ unsigned int st[4];
  __shared__ unsigned long long sh_base;

  const floatx4* s4 = (const floatx4*)(scores + (size_t)b*HWS);
  floatx4* c4 = (floatx4*)sc;
#pragma unroll
  for (int i = 0; i < 16; ++i) c4[i*64 + lane] = s4[i*64 + lane];
  __syncthreads();

  for (int i = 0; i < 64; ++i) {
    int idx = i*64 + lane;
    int y = i, x = lane;
    float c0 = sc[idx];
    float v = c0;
    if (y >= 1 && y <= 62 && x >= 1 && x <= 62) {
      bool ismax = (c0 > sc[idx-64]) && (c0 >= sc[idx+64]) &&
                   (c0 > sc[idx-1])  && (c0 >= sc[idx+1]);
      if (!ismax) v = c0 - 1e9f;
    }
    unsigned u = __float_as_uint(v);
    u = (u & 0x80000000u) ? ~u : (u | 0x80000000u);
    kx[idx] = (((unsigned long long)u) << 12) | (unsigned long long)(4095 - idx);
  }
  __syncthreads();

  unsigned long long base = 0;
  unsigned int need = 150, C = 0;
  for (int s = 36; s >= 4; s -= 8) {
    for (int i = lane; i < 256; i += 64) hist[i] = 0;
    __syncthreads();
    unsigned long long pref = base >> (s + 8);
    for (int i = 0; i < 64; ++i) {
      unsigned long long k = kx[i*64 + lane];
      if ((k >> (s + 8)) == pref) atomicAdd(&hist[(unsigned)(k >> s) & 255u], 1u);
    }
    __syncthreads();
    if (lane == 0) {
      unsigned cum = 0; int B = 0;
      for (int bin = 255; bin >= 0; --bin) {
        cum += hist[bin];
        if (cum >= need) { B = bin; break; }
      }
      st[0] = (150u - need) + cum;
      st[1] = need - (cum - hist[B]);
      sh_base = base | ((unsigned long long)B << s);
    }
    __syncthreads();
    C = st[0]; need = st[1]; base = sh_base;
    if (C <= 256u) break;
  }

  if (lane == 0) st[2] = 0;
  __syncthreads();
  for (int i = 0; i < 64; ++i) {
    unsigned long long k = kx[i*64 + lane];
    if (k >= base) {
      unsigned p = atomicAdd(&st[2], 1u);
      list[p] = k;
    }
  }
  __syncthreads();
  for (int i = lane; i < 256; i += 64) if (i >= (int)C) list[i] = 0ull;
  __syncthreads();

  for (int kk = 2; kk <= 256; kk <<= 1) {
    for (int j = kk >> 1; j > 0; j >>= 1) {
#pragma unroll
      for (int tt = 0; tt < 2; ++tt) {
        int t = lane + tt*64;
        int i2 = ((t & ~(j - 1)) << 1) | (t & (j - 1));
        int p2 = i2 | j;
        bool desc = ((i2 & kk) == 0);
        unsigned long long a = list[i2], c = list[p2];
        bool sw = desc ? (a < c) : (a > c);
        if (sw) { list[i2] = c; list[p2] = a; }
      }
      __syncthreads();
    }
  }

  for (int q = lane; q < 150; q += 64)
    qids[b*150 + q] = 4095 - (int)(list[q] & 0xFFFull);
}

// ---- fused flash attention v12: v9 per-wave schedule (proven no-spill at
//      VGPR=256) at 2 blocks/CU. Round-8 counters: 1 wave/SIMD left every
//      pipe at ~1/3 (MfmaUtil 23.6, VALU 34, per-CU L2 72 of ~135 GB/s).
//      VGPR=256 admits 2 waves/SIMD; only the grid blocked it. v12: KV range
//      split in QUARTERS (16-17 tiles); the two quarters of the SAME 32 rows
//      are waves (w, w+2) of one block; 512 blocks = 2/CU. Quarter partials
//      combine in-block via LDS (3 rounds, +1-pad stride -> conflict-free),
//      so global partial buffers/finalize are unchanged. Per-CU L2 traffic
//      unchanged. launch_bounds(256,2) pins regalloc at 256.
__global__ __launch_bounds__(256, 2) void flash_kernel(
    const unsigned short* __restrict__ Tb, const unsigned short* __restrict__ Kt,
    const unsigned short* __restrict__ Kf, const unsigned short* __restrict__ Vf,
    const float* __restrict__ mask, const float* __restrict__ colb,
    float* __restrict__ acc0, float* __restrict__ accH, float* __restrict__ lsums) {
  int blk = blockIdx.x;                       // 512 blocks
  int b    = (blk & 7) >> 1;                  // batch pinned to XCD pair
  int half = blk & 1;                         // KV half pinned to XCD
  int g    = blk >> 3;                        // row-group-64 [0,64)
  int tid = threadIdx.x;
  int wave = tid >> 6, lane = tid & 63;
  int rowset = wave & 1;                      // which 32-row set of the 64
  int quart  = wave >> 1;                     // which quarter of the KV half
  int lo = lane & 15, hi = lane >> 4;
  int n0 = g*64 + rowset*32;                  // this wave's 32 Q-rows
  int h0 = half ? 33 : 0, h1 = half ? NTIL : 33;
  int mid = (h0 + h1 + 1) >> 1;               // 17 / 49
  int t0 = quart ? mid : h0;
  int t1 = quart ? h1  : mid;

  __shared__ unsigned short pbuf[4][1152];    // per-wave P / M-exchange
  __shared__ float comb[2][64*65];            // pair-combine, +1-padded stride
  unsigned short* plw = &pbuf[wave][0];

  // Q fragments for this wave's two row-groups
  short8 q0[8], q1[8];
  const unsigned short* tb0 = Tb + ((size_t)b*HWS + n0 + lo)*CC + hi*8;
#pragma unroll
  for (int k = 0; k < 8; ++k) { q0[k] = ld8(tb0 + k*32); q1[k] = ld8(tb0 + 16*CC + k*32); }

  const unsigned short* kfb = Kf + (size_t)b*NTIL*16384 + lane*8;
  const unsigned short* vfb = Vf + (size_t)b*NTIL*16384 + lane*8;

  // prologue staging: kaA(t0) -> X, kaB(t0) -> Y (overlaps prologue dots)
  short8 X[16], Y[16];
#pragma unroll
  for (int i = 0; i < 16; ++i) X[i] = ld8(kfb + (size_t)t0*16384 + i*512);
#pragma unroll
  for (int i = 0; i < 16; ++i) Y[i] = ld8(kfb + (size_t)t0*16384 + (16 + i)*512);

  const float* mk = mask + b*HWS;

  // ---- prologue: diag and exe dots (fp32), fixed row max M = pick + 2
  float crb0[4], Msub0[4], crb1[4], Msub1[4];
  {
    const unsigned short* kep = Kt + ((size_t)b*MPAD + HWS)*CC + hi*8;
    // row-group 0
    float ddot = 0.f, edot = 0.f;
    const unsigned short* kdp = Kt + ((size_t)b*MPAD + n0 + lo)*CC + hi*8;
#pragma unroll
    for (int k = 0; k < 8; ++k) {
      short8 kd = ld8(kdp + k*32);
      short8 ke = ld8(kep + k*32);
#pragma unroll
      for (int j = 0; j < 8; ++j) {
        float qf = b2f((unsigned short)q0[k][j]);
        ddot = fmaf(qf, b2f((unsigned short)kd[j]), ddot);
        edot = fmaf(qf, b2f((unsigned short)ke[j]), edot);
      }
    }
    ddot += __shfl_xor(ddot, 16); ddot += __shfl_xor(ddot, 32);
    edot += __shfl_xor(edot, 16); edot += __shfl_xor(edot, 32);
    float Mrow = ((mk[n0 + lo] == 1.0f) ? ddot : edot) + 2.0f;
    float* fM = (float*)plw;
    fM[lo] = Mrow;
#pragma unroll
    for (int r = 0; r < 4; ++r) {
      Msub0[r] = fM[hi*4 + r];
      crb0[r]  = (mk[n0 + hi*4 + r] - 1.0f)*1e9f - Msub0[r];
    }
    // row-group 1
    ddot = 0.f; edot = 0.f;
    const unsigned short* kdp1 = Kt + ((size_t)b*MPAD + n0 + 16 + lo)*CC + hi*8;
#pragma unroll
    for (int k = 0; k < 8; ++k) {
      short8 kd = ld8(kdp1 + k*32);
      short8 ke = ld8(kep + k*32);
#pragma unroll
      for (int j = 0; j < 8; ++j) {
        float qf = b2f((unsigned short)q1[k][j]);
        ddot = fmaf(qf, b2f((unsigned short)kd[j]), ddot);
        edot = fmaf(qf, b2f((unsigned short)ke[j]), edot);
      }
    }
    ddot += __shfl_xor(ddot, 16); ddot += __shfl_xor(ddot, 32);
    edot += __shfl_xor(edot, 16); edot += __shfl_xor(edot, 32);
    float Mrow1 = ((mk[n0 + 16 + lo] == 1.0f) ? ddot : edot) + 2.0f;
    fM[lo] = Mrow1;
#pragma unroll
    for (int r = 0; r < 4; ++r) {
      Msub1[r] = fM[hi*4 + r];
      crb1[r]  = (mk[n0 + 16 + hi*4 + r] - 1.0f)*1e9f - Msub1[r];
    }
  }

  float lsum0[4] = {0.f, 0.f, 0.f, 0.f};
  float lsum1[4] = {0.f, 0.f, 0.f, 0.f};
  floatx4 o0[16] = {};
  floatx4 o1[16] = {};
  const float* cbb = colb + b*MPAD;

  for (int mt = t0; mt < t1; ++mt) {
    int m0 = mt*64;
    const unsigned short* vs = vfb + (size_t)mt*16384;
    // ---- QK-A: K slots 0..15 (k=0..3) from X; each fragment feeds both groups
    floatx4 s0[4] = {}, s1[4] = {};
#pragma unroll
    for (int k = 0; k < 4; ++k)
#pragma unroll
      for (int t = 0; t < 4; ++t) {
        s0[t] = __builtin_amdgcn_mfma_f32_16x16x32_bf16(q0[k], X[k*4 + t], s0[t], 0, 0, 0);
        s1[t] = __builtin_amdgcn_mfma_f32_16x16x32_bf16(q1[k], X[k*4 + t], s1[t], 0, 0, 0);
      }
    // issue vaA(mt) -> X (X dead after QK-A)
#pragma unroll
    for (int i = 0; i < 16; ++i) X[i] = ld8(vs + i*512);
    // ---- QK-B: K slots 16..31 (k=4..7) from Y
#pragma unroll
    for (int k = 4; k < 8; ++k)
#pragma unroll
      for (int t = 0; t < 4; ++t) {
        s0[t] = __builtin_amdgcn_mfma_f32_16x16x32_bf16(q0[k], Y[(k-4)*4 + t], s0[t], 0, 0, 0);
        s1[t] = __builtin_amdgcn_mfma_f32_16x16x32_bf16(q1[k], Y[(k-4)*4 + t], s1[t], 0, 0, 0);
      }
    // issue vaB(mt) -> Y (Y dead after QK-B)
#pragma unroll
    for (int i = 0; i < 16; ++i) Y[i] = ld8(vs + (16 + i)*512);
    // ---- fixed-max softmax: p = exp(s + colb[m] + rowb[r] - M_r)
    float cb[4];
#pragma unroll
    for (int t = 0; t < 4; ++t) cb[t] = cbb[m0 + t*16 + lo];
    short8 pf00, pf01, pf10, pf11;
    { // row-group 0
      float pr[4][4];
#pragma unroll
      for (int t = 0; t < 4; ++t)
#pragma unroll
        for (int r = 0; r < 4; ++r)
          pr[t][r] = s0[t][r] + cb[t] + crb0[r];
      if (mt == NTIL-1 && lo == 0) {
        // exe column (m==4096, t==0): never row-masked -> drop rowb
#pragma unroll
        for (int r = 0; r < 4; ++r) pr[0][r] = s0[0][r] - Msub0[r];
      }
#pragma unroll
      for (int t = 0; t < 4; ++t)
#pragma unroll
        for (int r = 0; r < 4; ++r) {
          float p = __expf(pr[t][r]);
          lsum0[r] += p;
          plw[(hi*4 + r)*72 + t*16 + lo] = f2b(p);
        }
      pf00 = *(const short8*)&plw[lo*72 + hi*8];
      pf01 = *(const short8*)&plw[lo*72 + 32 + hi*8];
    }
    { // row-group 1
      float pr[4][4];
#pragma unroll
      for (int t = 0; t < 4; ++t)
#pragma unroll
        for (int r = 0; r < 4; ++r)
          pr[t][r] = s1[t][r] + cb[t] + crb1[r];
      if (mt == NTIL-1 && lo == 0) {
#pragma unroll
        for (int r = 0; r < 4; ++r) pr[0][r] = s1[0][r] - Msub1[r];
      }
#pragma unroll
      for (int t = 0; t < 4; ++t)
#pragma unroll
        for (int r = 0; r < 4; ++r) {
          float p = __expf(pr[t][r]);
          lsum1[r] += p;
          plw[(hi*4 + r)*72 + t*16 + lo] = f2b(p);
        }
      pf10 = *(const short8*)&plw[lo*72 + hi*8];
      pf11 = *(const short8*)&plw[lo*72 + 32 + hi*8];
    }
    // ---- PV-A: V slots 0..15 (m 0..31) from X
#pragma unroll
    for (int sl = 0; sl < 16; ++sl) {
      o0[sl] = __builtin_amdgcn_mfma_f32_16x16x32_bf16(pf00, X[sl], o0[sl], 0, 0, 0);
      o1[sl] = __builtin_amdgcn_mfma_f32_16x16x32_bf16(pf10, X[sl], o1[sl], 0, 0, 0);
    }
    // issue kaA(mt+1) -> X
    if (mt + 1 < t1) {
      const unsigned short* ks = kfb + (size_t)(mt+1)*16384;
#pragma unroll
      for (int i = 0; i < 16; ++i) X[i] = ld8(ks + i*512);
    }
    // ---- PV-B: V slots 16..31 (m 32..63) from Y
#pragma unroll
    for (int sl = 0; sl < 16; ++sl) {
      o0[sl] = __builtin_amdgcn_mfma_f32_16x16x32_bf16(pf01, Y[sl], o0[sl], 0, 0, 0);
      o1[sl] = __builtin_amdgcn_mfma_f32_16x16x32_bf16(pf11, Y[sl], o1[sl], 0, 0, 0);
    }
    // issue kaB(mt+1) -> Y
    if (mt + 1 < t1) {
      const unsigned short* ks = kfb + (size_t)(mt+1)*16384;
#pragma unroll
      for (int i = 0; i < 16; ++i) Y[i] = ld8(ks + (16 + i)*512);
    }
  }

  // ---- in-block pair combine: quart0 -> LDS, quart1 += (3 rounds)
  // round 1: o0
  if (quart == 0) {
#pragma unroll
    for (int t = 0; t < 16; ++t)
#pragma unroll
      for (int r = 0; r < 4; ++r)
        comb[rowset][lane*65 + t*4 + r] = o0[t][r];
  }
  __syncthreads();
  if (quart == 1) {
#pragma unroll
    for (int t = 0; t < 16; ++t)
#pragma unroll
      for (int r = 0; r < 4; ++r)
        o0[t][r] += comb[rowset][lane*65 + t*4 + r];
  }
  __syncthreads();
  // round 2: o1
  if (quart == 0) {
#pragma unroll
    for (int t = 0; t < 16; ++t)
#pragma unroll
      for (int r = 0; r < 4; ++r)
        comb[rowset][lane*65 + t*4 + r] = o1[t][r];
  }
  __syncthreads();
  if (quart == 1) {
#pragma unroll
    for (int t = 0; t < 16; ++t)
#pragma unroll
      for (int r = 0; r < 4; ++r)
        o1[t][r] += comb[rowset][lane*65 + t*4 + r];
  }
  __syncthreads();
  // round 3: lsums (8 floats/lane)
  if (quart == 0) {
#pragma unroll
    for (int r = 0; r < 4; ++r) {
      comb[rowset][lane*65 + r]     = lsum0[r];
      comb[rowset][lane*65 + 4 + r] = lsum1[r];
    }
  }
  __syncthreads();
  if (quart == 0) return;                     // quart1 owns the epilogue
#pragma unroll
  for (int r = 0; r < 4; ++r) {
    lsum0[r] += comb[rowset][lane*65 + r];
    lsum1[r] += comb[rowset][lane*65 + 4 + r];
  }

  // ---- l reduction over the 16 lo lanes (both groups)
#pragma unroll
  for (int r = 0; r < 4; ++r) {
#pragma unroll
    for (int off = 1; off < 16; off <<= 1) {
      lsum0[r] += __shfl_xor(lsum0[r], off);
      lsum1[r] += __shfl_xor(lsum1[r], off);
    }
  }
  // ---- epilogue: scatter fp32 UNNORMALIZED partials (no rounding here)
  float* op = (half ? accH : acc0) + (size_t)b*CC*HWS;
#pragma unroll
  for (int t = 0; t < 16; ++t)
#pragma unroll
    for (int r = 0; r < 4; ++r) {
      op[(size_t)(t*16 + lo)*HWS + n0 + hi*4 + r]      = o0[t][r];
      op[(size_t)(t*16 + lo)*HWS + n0 + 16 + hi*4 + r] = o1[t][r];
    }
  if (lo == 0) {
    float* lp = lsums + ((size_t)(half*NB + b))*HWS;
#pragma unroll
    for (int r = 0; r < 4; ++r) {
      lp[n0 + hi*4 + r]      = lsum0[r];
      lp[n0 + 16 + hi*4 + r] = lsum1[r];
    }
  }
}

// ---- out0[b][d][n] = bf16_round( (p0+p1) * 1/(l0+l1) ) + img  (coalesced)
__global__ __launch_bounds__(256) void finalize_kernel(const float* __restrict__ accH,
    const float* __restrict__ lsums, const float* __restrict__ img,
    float* __restrict__ out0) {
  int b = blockIdx.x >> 8;
  int d = blockIdx.x & 255;
  size_t base = ((size_t)b*CC + d)*HWS;
  const float* l0 = lsums + (size_t)b*HWS;
  const float* l1 = lsums + (size_t)(NB + b)*HWS;
  for (int n = threadIdx.x; n < HWS; n += 256) {
    float inv = 1.0f / (l0[n] + l1[n]);
    float o = (out0[base + n] + accH[base + n]) * inv;
    out0[base + n] = b2f(f2b(o)) + img[base + n];
  }
}

// ---- queries[b][q][d] = sum_c img[b][c][id]*v_w[d][c]  (fp32 seq FMA)
__global__ __launch_bounds__(256) void gather_kernel(const float* __restrict__ img,
    const float* __restrict__ vw, const int* __restrict__ qids, float* __restrict__ out1) {
  int blk = blockIdx.x;
  int b = blk / 150, q = blk % 150;
  int dd = threadIdx.x;
  __shared__ float col[CC];
  int id = qids[b*150 + q];
  col[dd] = img[((size_t)b*CC + dd)*HWS + id];
  __syncthreads();
  const float* vr = vw + dd*CC;
  float acc = 0.f;
  for (int c = 0; c < CC; ++c) acc = fmaf(col[c], vr[c], acc);
  out1[((size_t)(b*150 + q))*CC + dd] = acc;
}

extern "C" void kernel_launch(void* const* d_in, const int* in_sizes, int n_in,
                              void* d_out, int out_size, void* d_ws, size_t ws_size,
                              hipStream_t stream) {
  const float* img  = (const float*)d_in[0];
  const float* exe  = (const float*)d_in[1];
  const float* mask = (const float*)d_in[2];
  const float* sim  = (const float*)d_in[3];
  const float* vw   = (const float*)d_in[4];
  float* out0 = (float*)d_out;
  float* out1 = out0 + (size_t)NB*CC*HWS;

  char* ws = (char*)d_ws;
  size_t o = 0;
  unsigned short* Kt  = (unsigned short*)(ws + o); o += (size_t)NB*MPAD*CC*2;
  unsigned short* Tb  = (unsigned short*)(ws + o); o += (size_t)NB*HWS*CC*2;
  unsigned short* Kf  = (unsigned short*)(ws + o); o += (size_t)NB*NTIL*16384*2;
  unsigned short* Vf  = (unsigned short*)(ws + o); o += (size_t)NB*NTIL*16384*2;
  unsigned short* St  = (unsigned short*)(ws + o); o += (size_t)CC*CC*2;
  unsigned short* Vw  = (unsigned short*)(ws + o); o += (size_t)CC*CC*2;
  float*          scores = (float*)(ws + o);       o += (size_t)NB*HWS*4;
  float*          colb   = (float*)(ws + o);       o += (size_t)NB*MPAD*4;
  int*            qids   = (int*)(ws + o);         o += (size_t)NB*150*4;
  float*          accH   = (float*)(ws + o);       o += (size_t)NB*CC*HWS*4;
  float*          lsums  = (float*)(ws + o);       o += (size_t)2*NB*HWS*4;

  prep_colb  <<<dim3(CC + NB),    dim3(256), 0, stream>>>(sim, vw, mask, St, Vw, colb);
  build_kt   <<<dim3(NB, 65, 4),  dim3(256), 0, stream>>>(img, exe, Kt, Kf);
  gemm_small <<<dim3(NB, 64, 4),  dim3(256), 0, stream>>>(Kt, St, Tb, nullptr, 0);
  gemm_small <<<dim3(NB, 65, 4),  dim3(256), 0, stream>>>(Kt, Vw, nullptr, Vf, 1);
  scores_kernel<<<dim3(NB, 128),  dim3(256), 0, stream>>>(img, sim, exe, scores);
  select_kernel<<<dim3(NB),       dim3(64),  0, stream>>>(scores, qids);
  flash_kernel <<<dim3(512),      dim3(256), 0, stream>>>(Tb, Kt, Kf, Vf, mask, colb,
                                                          out0, accH, lsums);
  finalize_kernel<<<dim3(NB*CC),  dim3(256), 0, stream>>>(accH, lsums, img, out0);
  gather_kernel<<<dim3(NB*150),   dim3(256), 0, stream>>>(img, vw, qids, out1);
}

// Round 10
// 393.180 us; speedup vs baseline: 2.0575x; 2.0575x over previous
//
#include <hip/hip_runtime.h>

#define CC   256
#define HWS  4096
#define MPAD 4160   // 65*64, rows >= 4097 zero-padded
#define NB   4
#define NTIL 65

typedef __attribute__((ext_vector_type(8))) short   short8;
typedef __attribute__((ext_vector_type(4))) float   floatx4;

static __device__ __forceinline__ short8 ld8(const unsigned short* p) {
  return *(const short8*)p;
}
static __device__ __forceinline__ void st8(unsigned short* p, short8 v) {
  *(short8*)p = v;
}
static __device__ __forceinline__ unsigned short f2b(float x) {
  union { float f; unsigned u; } v; v.f = x;
  unsigned r = v.u + 0x7FFFu + ((v.u >> 16) & 1u);
  return (unsigned short)(r >> 16);
}
static __device__ __forceinline__ float b2f(unsigned short x) {
  union { unsigned u; float f; } v; v.u = ((unsigned)x) << 16;
  return v.f;
}

// ---- merged: St[d][c] = sim[c][d], Vw[d][c] = v_w[d][c] (bf16); colb biases
__global__ void prep_colb(const float* __restrict__ sim, const float* __restrict__ vw,
                          const float* __restrict__ mask,
                          unsigned short* __restrict__ St, unsigned short* __restrict__ Vw,
                          float* __restrict__ colb) {
  int blk = blockIdx.x, tid = threadIdx.x;
  if (blk < CC) {
    int dd = blk, c = tid;
    St[dd*CC + c] = f2b(sim[c*CC + dd]);
    Vw[dd*CC + c] = f2b(vw[dd*CC + c]);
    return;
  }
  int b = blk - CC;
  for (int m = tid; m < MPAD; m += 256) {
    float v;
    if (m < HWS)      v = (mask[b*HWS + m] - 1.0f) * 1e9f;
    else if (m == HWS) v = 0.0f;
    else               v = -3.0e38f;
    colb[b*MPAD + m] = v;
  }
}

// ---- Kt[b][m][d] = bf16(concat[b][d][m]); ALSO writes Kf fragment-major
__global__ void build_kt(const float* __restrict__ img, const float* __restrict__ exe,
                         unsigned short* __restrict__ Kt, unsigned short* __restrict__ Kf) {
  int b = blockIdx.x, mt = blockIdx.y, dt = blockIdx.z;
  int tid = threadIdx.x;
  int m0 = mt*64, d0 = dt*64;
  int w = tid >> 6, lane = tid & 63, lo = lane & 15, hi = lane >> 4;
  unsigned short* kft = Kf + (size_t)(b*NTIL + mt)*16384;
  if (mt == 64) {
    for (int i = 0; i < 16; ++i) {
      int m = m0 + (tid>>6) + i*4;
      int d = d0 + (tid&63);
      unsigned short v = 0;
      if (m == 4096) v = f2b(1.2f * exe[b*CC + d]);
      Kt[((size_t)b*MPAD + m)*CC + d] = v;
    }
#pragma unroll
    for (int ss = 0; ss < 2; ++ss) {
      int s = dt*8 + w*2 + ss;
      int k = s >> 2, t = s & 3;
      unsigned short tmp[8] = {0,0,0,0,0,0,0,0};
      if (t == 0 && lo == 0) {
#pragma unroll
        for (int j = 0; j < 8; ++j)
          tmp[j] = f2b(1.2f * exe[b*CC + k*32 + hi*8 + j]);
      }
      st8(kft + s*512 + lane*8, *(short8*)tmp);
    }
    return;
  }
  __shared__ float tile[64][65];
  for (int i = 0; i < 16; ++i) {
    int dl = (tid>>6) + i*4, ml = tid&63;
    tile[dl][ml] = img[((size_t)b*CC + d0+dl)*HWS + m0+ml];
  }
  __syncthreads();
  for (int i = 0; i < 16; ++i) {
    int ml = (tid>>6) + i*4, dl = tid&63;
    Kt[((size_t)b*MPAD + m0+ml)*CC + d0+dl] = f2b(tile[dl][ml]);
  }
#pragma unroll
  for (int ss = 0; ss < 2; ++ss) {
    int s = dt*8 + w*2 + ss;
    int k = s >> 2, t = s & 3;
    int ml = t*16 + lo;
    int dlb = (k - dt*2)*32 + hi*8;
    unsigned short tmp[8];
#pragma unroll
    for (int j = 0; j < 8; ++j) tmp[j] = f2b(tile[dlb + j][ml]);
    st8(kft + s*512 + lane*8, *(short8*)tmp);
  }
}

// ---- mode 0: Tb[b][n][d] = bf16( sum_c Kt[n][c]*St[d][c] )
// ---- mode 1: Vf fragment-major = bf16( sum_c Kt[m][c]*Vw[d][c] )
//      A-fragments read from Kf (same bytes as Kt rows, but wave-contiguous
//      1KB slots: Kf[by][(k*4+w)*512+lane*8] == Kt[(by*64+w*16+lo)*CC+k*32+hi*8]).
__global__ __launch_bounds__(256) void gemm_small(const unsigned short* __restrict__ Kf,
    const unsigned short* __restrict__ Bm, unsigned short* __restrict__ Tout,
    unsigned short* __restrict__ Vf, int b, int mode) {
  int by = blockIdx.y;
  int w  = threadIdx.x >> 6;
  int c0 = blockIdx.z*64;
  int lane = threadIdx.x & 63;
  int lo = lane & 15, hi = lane >> 4;
  __shared__ unsigned short lsh[64][72];
  floatx4 acc[4] = {};
  const unsigned short* kft = Kf + (size_t)(b*NTIL + by)*16384 + lane*8;
#pragma unroll
  for (int k = 0; k < 8; ++k) {
    short8 af = ld8(kft + (k*4 + w)*512);
#pragma unroll
    for (int t = 0; t < 4; ++t) {
      short8 bf = ld8(Bm + (size_t)(c0 + t*16 + lo)*CC + k*32 + hi*8);
      acc[t] = __builtin_amdgcn_mfma_f32_16x16x32_bf16(af, bf, acc[t], 0, 0, 0);
    }
  }
  if (mode == 0) {
#pragma unroll
    for (int t = 0; t < 4; ++t)
#pragma unroll
      for (int r = 0; r < 4; ++r)
        lsh[w*16 + hi*4 + r][t*16 + lo] = f2b(acc[t][r]);
    __syncthreads();
    int tid = threadIdx.x;
    int nl = tid >> 2, seg = tid & 3;
    unsigned short* dst = Tout + ((size_t)b*HWS + by*64 + nl)*CC + c0 + seg*16;
    st8(dst,     ld8(&lsh[nl][seg*16]));
    st8(dst + 8, ld8(&lsh[nl][seg*16 + 8]));
  } else {
#pragma unroll
    for (int t = 0; t < 4; ++t)
#pragma unroll
      for (int r = 0; r < 4; ++r)
        lsh[t*16 + lo][w*16 + hi*4 + r] = f2b(acc[t][r]);
    __syncthreads();
    unsigned short* vfb2 = Vf + (size_t)(b*NTIL + by)*16384;
#pragma unroll
    for (int ss = 0; ss < 2; ++ss) {
      int idx = w*2 + ss;            // [0,8)
      int h = idx >> 2, t4 = idx & 3;
      int s = h*16 + (c0 >> 4) + t4;
      short8 v = ld8(&lsh[t4*16 + (lane & 15)][h*32 + (lane >> 4)*8]);
      st8(vfb2 + s*512 + lane*8, v);
    }
  }
}

// ---- score mimicry of np/BLAS fp32 T-path, sequential FMA everywhere.
__global__ __launch_bounds__(256) void scores_kernel(const float* __restrict__ img,
    const float* __restrict__ sim, const float* __restrict__ exe,
    float* __restrict__ score32) {
  int b = blockIdx.x, n0 = blockIdx.y*32;
  int d = threadIdx.x;
  __shared__ float U[32][257];        // U[nl][c] = img[b, c, n0+nl]
  __shared__ float R[32][257];        // T32[nl][d]
  __shared__ float E[256];
  for (int idx = threadIdx.x; idx < 32*256; idx += 256) {
    int nl = idx & 31, c = idx >> 5;
    U[nl][c] = img[((size_t)b*CC + c)*HWS + n0 + nl];
  }
  E[d] = 1.2f * exe[b*CC + d];
  __syncthreads();
  float acc[32];
#pragma unroll
  for (int nl = 0; nl < 32; ++nl) acc[nl] = 0.f;
  for (int c = 0; c < CC; ++c) {
    float s_cd = sim[c*CC + d];
#pragma unroll
    for (int nl = 0; nl < 32; ++nl) acc[nl] = fmaf(U[nl][c], s_cd, acc[nl]);
  }
#pragma unroll
  for (int nl = 0; nl < 32; ++nl) R[nl][d] = acc[nl];
  __syncthreads();
  if (d < 32) {
    float s = 0.f;
    for (int dd = 0; dd < CC; ++dd) s = fmaf(R[d][dd], E[dd], s);
    score32[b*HWS + n0 + d] = s;
  }
}

// ---- top-150 via exact radix-select on distinct 44-bit keys + bitonic-256 sort.
__global__ __launch_bounds__(64) void select_kernel(const float* __restrict__ scores,
                                                    int* __restrict__ qids) {
  int b = blockIdx.x, lane = threadIdx.x;
  __shared__ float sc[HWS];
  __shared__ unsigned long long kx[HWS];
  __shared__ unsigned long long list[256];
  __shared__ unsigned int hist[256];
  __shared__ unsigned int st[4];
  __shared__ unsigned long long sh_base;

  const floatx4* s4 = (const floatx4*)(scores + (size_t)b*HWS);
  floatx4* c4 = (floatx4*)sc;
#pragma unroll
  for (int i = 0; i < 16; ++i) c4[i*64 + lane] = s4[i*64 + lane];
  __syncthreads();

  for (int i = 0; i < 64; ++i) {
    int idx = i*64 + lane;
    int y = i, x = lane;
    float c0 = sc[idx];
    float v = c0;
    if (y >= 1 && y <= 62 && x >= 1 && x <= 62) {
      bool ismax = (c0 > sc[idx-64]) && (c0 >= sc[idx+64]) &&
                   (c0 > sc[idx-1])  && (c0 >= sc[idx+1]);
      if (!ismax) v = c0 - 1e9f;
    }
    unsigned u = __float_as_uint(v);
    u = (u & 0x80000000u) ? ~u : (u | 0x80000000u);
    kx[idx] = (((unsigned long long)u) << 12) | (unsigned long long)(4095 - idx);
  }
  __syncthreads();

  unsigned long long base = 0;
  unsigned int need = 150, C = 0;
  for (int s = 36; s >= 4; s -= 8) {
    for (int i = lane; i < 256; i += 64) hist[i] = 0;
    __syncthreads();
    unsigned long long pref = base >> (s + 8);
    for (int i = 0; i < 64; ++i) {
      unsigned long long k = kx[i*64 + lane];
      if ((k >> (s + 8)) == pref) atomicAdd(&hist[(unsigned)(k >> s) & 255u], 1u);
    }
    __syncthreads();
    if (lane == 0) {
      unsigned cum = 0; int B = 0;
      for (int bin = 255; bin >= 0; --bin) {
        cum += hist[bin];
        if (cum >= need) { B = bin; break; }
      }
      st[0] = (150u - need) + cum;
      st[1] = need - (cum - hist[B]);
      sh_base = base | ((unsigned long long)B << s);
    }
    __syncthreads();
    C = st[0]; need = st[1]; base = sh_base;
    if (C <= 256u) break;
  }

  if (lane == 0) st[2] = 0;
  __syncthreads();
  for (int i = 0; i < 64; ++i) {
    unsigned long long k = kx[i*64 + lane];
    if (k >= base) {
      unsigned p = atomicAdd(&st[2], 1u);
      list[p] = k;
    }
  }
  __syncthreads();
  for (int i = lane; i < 256; i += 64) if (i >= (int)C) list[i] = 0ull;
  __syncthreads();

  for (int kk = 2; kk <= 256; kk <<= 1) {
    for (int j = kk >> 1; j > 0; j >>= 1) {
#pragma unroll
      for (int tt = 0; tt < 2; ++tt) {
        int t = lane + tt*64;
        int i2 = ((t & ~(j - 1)) << 1) | (t & (j - 1));
        int p2 = i2 | j;
        bool desc = ((i2 & kk) == 0);
        unsigned long long a = list[i2], c = list[p2];
        bool sw = desc ? (a < c) : (a > c);
        if (sw) { list[i2] = c; list[p2] = a; }
      }
      __syncthreads();
    }
  }

  for (int q = lane; q < 150; q += 64)
    qids[b*150 + q] = 4095 - (int)(list[q] & 0xFFFull);
}

// ---- fused flash attention v9 (FROZEN: proven 116us x3; occupancy ceiling is
//      1 wave/SIMD — real footprint ~400 of 512 unified regs/wave, so
//      2 waves/SIMD (v12) forced VGPR=128 + 2.5GB spill; whole-tile prefetch
//      (v11) overflowed liveness; LDS-sharing (v7) lost to barrier coupling.
//      Dual 16-row groups per wave + KV-half split + quarter-phase X/Y
//      register streaming + fixed-max softmax.)
__global__ __launch_bounds__(256, 1) void flash_kernel(
    const unsigned short* __restrict__ Tb, const unsigned short* __restrict__ Kt,
    const unsigned short* __restrict__ Kf, const unsigned short* __restrict__ Vf,
    const float* __restrict__ mask, const float* __restrict__ colb,
    float* __restrict__ acc0, float* __restrict__ accH, float* __restrict__ lsums) {
  int blk = blockIdx.x;                       // 256 blocks
  int b    = (blk & 7) >> 1;                  // batch pinned to XCD pair
  int half = blk & 1;                         // KV half pinned to XCD
  int g    = blk >> 3;                        // row-group-128 [0,32)
  int tid = threadIdx.x;
  int wave = tid >> 6, lane = tid & 63;
  int lo = lane & 15, hi = lane >> 4;
  int n0 = g*128 + wave*32;                   // this wave's 32 Q-rows
  int t0 = half ? 33 : 0, t1 = half ? NTIL : 33;

  __shared__ unsigned short pbuf[4][1152];    // per-wave P / M-exchange
  unsigned short* plw = &pbuf[wave][0];

  // Q fragments for this wave's two row-groups
  short8 q0[8], q1[8];
  const unsigned short* tb0 = Tb + ((size_t)b*HWS + n0 + lo)*CC + hi*8;
#pragma unroll
  for (int k = 0; k < 8; ++k) { q0[k] = ld8(tb0 + k*32); q1[k] = ld8(tb0 + 16*CC + k*32); }

  const unsigned short* kfb = Kf + (size_t)b*NTIL*16384 + lane*8;
  const unsigned short* vfb = Vf + (size_t)b*NTIL*16384 + lane*8;

  // prologue staging: kaA(t0) -> X, kaB(t0) -> Y (overlaps prologue dots)
  short8 X[16], Y[16];
#pragma unroll
  for (int i = 0; i < 16; ++i) X[i] = ld8(kfb + (size_t)t0*16384 + i*512);
#pragma unroll
  for (int i = 0; i < 16; ++i) Y[i] = ld8(kfb + (size_t)t0*16384 + (16 + i)*512);

  const float* mk = mask + b*HWS;

  // ---- prologue: diag and exe dots (fp32), fixed row max M = pick + 2
  float crb0[4], Msub0[4], crb1[4], Msub1[4];
  {
    const unsigned short* kep = Kt + ((size_t)b*MPAD + HWS)*CC + hi*8;
    // row-group 0
    float ddot = 0.f, edot = 0.f;
    const unsigned short* kdp = Kt + ((size_t)b*MPAD + n0 + lo)*CC + hi*8;
#pragma unroll
    for (int k = 0; k < 8; ++k) {
      short8 kd = ld8(kdp + k*32);
      short8 ke = ld8(kep + k*32);
#pragma unroll
      for (int j = 0; j < 8; ++j) {
        float qf = b2f((unsigned short)q0[k][j]);
        ddot = fmaf(qf, b2f((unsigned short)kd[j]), ddot);
        edot = fmaf(qf, b2f((unsigned short)ke[j]), edot);
      }
    }
    ddot += __shfl_xor(ddot, 16); ddot += __shfl_xor(ddot, 32);
    edot += __shfl_xor(edot, 16); edot += __shfl_xor(edot, 32);
    float Mrow = ((mk[n0 + lo] == 1.0f) ? ddot : edot) + 2.0f;
    float* fM = (float*)plw;
    fM[lo] = Mrow;
#pragma unroll
    for (int r = 0; r < 4; ++r) {
      Msub0[r] = fM[hi*4 + r];
      crb0[r]  = (mk[n0 + hi*4 + r] - 1.0f)*1e9f - Msub0[r];
    }
    // row-group 1
    ddot = 0.f; edot = 0.f;
    const unsigned short* kdp1 = Kt + ((size_t)b*MPAD + n0 + 16 + lo)*CC + hi*8;
#pragma unroll
    for (int k = 0; k < 8; ++k) {
      short8 kd = ld8(kdp1 + k*32);
      short8 ke = ld8(kep + k*32);
#pragma unroll
      for (int j = 0; j < 8; ++j) {
        float qf = b2f((unsigned short)q1[k][j]);
        ddot = fmaf(qf, b2f((unsigned short)kd[j]), ddot);
        edot = fmaf(qf, b2f((unsigned short)ke[j]), edot);
      }
    }
    ddot += __shfl_xor(ddot, 16); ddot += __shfl_xor(ddot, 32);
    edot += __shfl_xor(edot, 16); edot += __shfl_xor(edot, 32);
    float Mrow1 = ((mk[n0 + 16 + lo] == 1.0f) ? ddot : edot) + 2.0f;
    fM[lo] = Mrow1;
#pragma unroll
    for (int r = 0; r < 4; ++r) {
      Msub1[r] = fM[hi*4 + r];
      crb1[r]  = (mk[n0 + 16 + hi*4 + r] - 1.0f)*1e9f - Msub1[r];
    }
  }

  float lsum0[4] = {0.f, 0.f, 0.f, 0.f};
  float lsum1[4] = {0.f, 0.f, 0.f, 0.f};
  floatx4 o0[16] = {};
  floatx4 o1[16] = {};
  const float* cbb = colb + b*MPAD;

  for (int mt = t0; mt < t1; ++mt) {
    int m0 = mt*64;
    const unsigned short* vs = vfb + (size_t)mt*16384;
    // ---- QK-A: K slots 0..15 (k=0..3) from X; each fragment feeds both groups
    floatx4 s0[4] = {}, s1[4] = {};
#pragma unroll
    for (int k = 0; k < 4; ++k)
#pragma unroll
      for (int t = 0; t < 4; ++t) {
        s0[t] = __builtin_amdgcn_mfma_f32_16x16x32_bf16(q0[k], X[k*4 + t], s0[t], 0, 0, 0);
        s1[t] = __builtin_amdgcn_mfma_f32_16x16x32_bf16(q1[k], X[k*4 + t], s1[t], 0, 0, 0);
      }
    // issue vaA(mt) -> X (X dead after QK-A)
#pragma unroll
    for (int i = 0; i < 16; ++i) X[i] = ld8(vs + i*512);
    // ---- QK-B: K slots 16..31 (k=4..7) from Y
#pragma unroll
    for (int k = 4; k < 8; ++k)
#pragma unroll
      for (int t = 0; t < 4; ++t) {
        s0[t] = __builtin_amdgcn_mfma_f32_16x16x32_bf16(q0[k], Y[(k-4)*4 + t], s0[t], 0, 0, 0);
        s1[t] = __builtin_amdgcn_mfma_f32_16x16x32_bf16(q1[k], Y[(k-4)*4 + t], s1[t], 0, 0, 0);
      }
    // issue vaB(mt) -> Y (Y dead after QK-B)
#pragma unroll
    for (int i = 0; i < 16; ++i) Y[i] = ld8(vs + (16 + i)*512);
    // ---- fixed-max softmax: p = exp(s + colb[m] + rowb[r] - M_r)
    float cb[4];
#pragma unroll
    for (int t = 0; t < 4; ++t) cb[t] = cbb[m0 + t*16 + lo];
    short8 pf00, pf01, pf10, pf11;
    { // row-group 0
      float pr[4][4];
#pragma unroll
      for (int t = 0; t < 4; ++t)
#pragma unroll
        for (int r = 0; r < 4; ++r)
          pr[t][r] = s0[t][r] + cb[t] + crb0[r];
      if (mt == NTIL-1 && lo == 0) {
        // exe column (m==4096, t==0): never row-masked -> drop rowb
#pragma unroll
        for (int r = 0; r < 4; ++r) pr[0][r] = s0[0][r] - Msub0[r];
      }
#pragma unroll
      for (int t = 0; t < 4; ++t)
#pragma unroll
        for (int r = 0; r < 4; ++r) {
          float p = __expf(pr[t][r]);
          lsum0[r] += p;
          plw[(hi*4 + r)*72 + t*16 + lo] = f2b(p);
        }
      pf00 = *(const short8*)&plw[lo*72 + hi*8];
      pf01 = *(const short8*)&plw[lo*72 + 32 + hi*8];
    }
    { // row-group 1
      float pr[4][4];
#pragma unroll
      for (int t = 0; t < 4; ++t)
#pragma unroll
        for (int r = 0; r < 4; ++r)
          pr[t][r] = s1[t][r] + cb[t] + crb1[r];
      if (mt == NTIL-1 && lo == 0) {
#pragma unroll
        for (int r = 0; r < 4; ++r) pr[0][r] = s1[0][r] - Msub1[r];
      }
#pragma unroll
      for (int t = 0; t < 4; ++t)
#pragma unroll
        for (int r = 0; r < 4; ++r) {
          float p = __expf(pr[t][r]);
          lsum1[r] += p;
          plw[(hi*4 + r)*72 + t*16 + lo] = f2b(p);
        }
      pf10 = *(const short8*)&plw[lo*72 + hi*8];
      pf11 = *(const short8*)&plw[lo*72 + 32 + hi*8];
    }
    // ---- PV-A: V slots 0..15 (m 0..31) from X
#pragma unroll
    for (int sl = 0; sl < 16; ++sl) {
      o0[sl] = __builtin_amdgcn_mfma_f32_16x16x32_bf16(pf00, X[sl], o0[sl], 0, 0, 0);
      o1[sl] = __builtin_amdgcn_mfma_f32_16x16x32_bf16(pf10, X[sl], o1[sl], 0, 0, 0);
    }
    // issue kaA(mt+1) -> X
    if (mt + 1 < t1) {
      const unsigned short* ks = kfb + (size_t)(mt+1)*16384;
#pragma unroll
      for (int i = 0; i < 16; ++i) X[i] = ld8(ks + i*512);
    }
    // ---- PV-B: V slots 16..31 (m 32..63) from Y
#pragma unroll
    for (int sl = 0; sl < 16; ++sl) {
      o0[sl] = __builtin_amdgcn_mfma_f32_16x16x32_bf16(pf01, Y[sl], o0[sl], 0, 0, 0);
      o1[sl] = __builtin_amdgcn_mfma_f32_16x16x32_bf16(pf11, Y[sl], o1[sl], 0, 0, 0);
    }
    // issue kaB(mt+1) -> Y
    if (mt + 1 < t1) {
      const unsigned short* ks = kfb + (size_t)(mt+1)*16384;
#pragma unroll
      for (int i = 0; i < 16; ++i) Y[i] = ld8(ks + (16 + i)*512);
    }
  }
  // ---- l reduction over the 16 lo lanes (both groups)
#pragma unroll
  for (int r = 0; r < 4; ++r) {
#pragma unroll
    for (int off = 1; off < 16; off <<= 1) {
      lsum0[r] += __shfl_xor(lsum0[r], off);
      lsum1[r] += __shfl_xor(lsum1[r], off);
    }
  }
  // ---- epilogue: scatter fp32 UNNORMALIZED partials (no rounding here)
  float* op = (half ? accH : acc0) + (size_t)b*CC*HWS;
#pragma unroll
  for (int t = 0; t < 16; ++t)
#pragma unroll
    for (int r = 0; r < 4; ++r) {
      op[(size_t)(t*16 + lo)*HWS + n0 + hi*4 + r]      = o0[t][r];
      op[(size_t)(t*16 + lo)*HWS + n0 + 16 + hi*4 + r] = o1[t][r];
    }
  if (lo == 0) {
    float* lp = lsums + ((size_t)(half*NB + b))*HWS;
#pragma unroll
    for (int r = 0; r < 4; ++r) {
      lp[n0 + hi*4 + r]      = lsum0[r];
      lp[n0 + 16 + hi*4 + r] = lsum1[r];
    }
  }
}

// ---- out0[b][d][n] = bf16_round( (p0+p1) * 1/(l0+l1) ) + img  (coalesced)
__global__ __launch_bounds__(256) void finalize_kernel(const float* __restrict__ accH,
    const float* __restrict__ lsums, const float* __restrict__ img,
    float* __restrict__ out0) {
  int b = blockIdx.x >> 8;
  int d = blockIdx.x & 255;
  size_t base = ((size_t)b*CC + d)*HWS;
  const float* l0 = lsums + (size_t)b*HWS;
  const float* l1 = lsums + (size_t)(NB + b)*HWS;
  for (int n = threadIdx.x; n < HWS; n += 256) {
    float inv = 1.0f / (l0[n] + l1[n]);
    float o = (out0[base + n] + accH[base + n]) * inv;
    out0[base + n] = b2f(f2b(o)) + img[base + n];
  }
}

// ---- queries[b][q][d] = sum_c img[b][c][id]*v_w[d][c]  (fp32 seq FMA)
__global__ __launch_bounds__(256) void gather_kernel(const float* __restrict__ img,
    const float* __restrict__ vw, const int* __restrict__ qids, float* __restrict__ out1) {
  int blk = blockIdx.x;
  int b = blk / 150, q = blk % 150;
  int dd = threadIdx.x;
  __shared__ float col[CC];
  int id = qids[b*150 + q];
  col[dd] = img[((size_t)b*CC + dd)*HWS + id];
  __syncthreads();
  const float* vr = vw + dd*CC;
  float acc = 0.f;
  for (int c = 0; c < CC; ++c) acc = fmaf(col[c], vr[c], acc);
  out1[((size_t)(b*150 + q))*CC + dd] = acc;
}

extern "C" void kernel_launch(void* const* d_in, const int* in_sizes, int n_in,
                              void* d_out, int out_size, void* d_ws, size_t ws_size,
                              hipStream_t stream) {
  const float* img  = (const float*)d_in[0];
  const float* exe  = (const float*)d_in[1];
  const float* mask = (const float*)d_in[2];
  const float* sim  = (const float*)d_in[3];
  const float* vw   = (const float*)d_in[4];
  float* out0 = (float*)d_out;
  float* out1 = out0 + (size_t)NB*CC*HWS;

  char* ws = (char*)d_ws;
  size_t o = 0;
  unsigned short* Kt  = (unsigned short*)(ws + o); o += (size_t)NB*MPAD*CC*2;
  unsigned short* Tb  = (unsigned short*)(ws + o); o += (size_t)NB*HWS*CC*2;
  unsigned short* Kf  = (unsigned short*)(ws + o); o += (size_t)NB*NTIL*16384*2;
  unsigned short* Vf  = (unsigned short*)(ws + o); o += (size_t)NB*NTIL*16384*2;
  unsigned short* St  = (unsigned short*)(ws + o); o += (size_t)CC*CC*2;
  unsigned short* Vw  = (unsigned short*)(ws + o); o += (size_t)CC*CC*2;
  float*          scores = (float*)(ws + o);       o += (size_t)NB*HWS*4;
  float*          colb   = (float*)(ws + o);       o += (size_t)NB*MPAD*4;
  int*            qids   = (int*)(ws + o);         o += (size_t)NB*150*4;
  float*          accH   = (float*)(ws + o);       o += (size_t)NB*CC*HWS*4;
  float*          lsums  = (float*)(ws + o);       o += (size_t)2*NB*HWS*4;

  prep_colb  <<<dim3(CC + NB),    dim3(256), 0, stream>>>(sim, vw, mask, St, Vw, colb);
  build_kt   <<<dim3(NB, 65, 4),  dim3(256), 0, stream>>>(img, exe, Kt, Kf);
  for (int b = 0; b < NB; ++b) {
    gemm_small <<<dim3(1, 64, 4),  dim3(256), 0, stream>>>(Kf, St, Tb, nullptr, b, 0);
    gemm_small <<<dim3(1, 65, 4),  dim3(256), 0, stream>>>(Kf, Vw, nullptr, Vf, b, 1);
  }
  scores_kernel<<<dim3(NB, 128),  dim3(256), 0, stream>>>(img, sim, exe, scores);
  select_kernel<<<dim3(NB),       dim3(64),  0, stream>>>(scores, qids);
  flash_kernel <<<dim3(256),      dim3(256), 0, stream>>>(Tb, Kt, Kf, Vf, mask, colb,
                                                          out0, accH, lsums);
  finalize_kernel<<<dim3(NB*CC),  dim3(256), 0, stream>>>(accH, lsums, img, out0);
  gather_kernel<<<dim3(NB*150),   dim3(256), 0, stream>>>(img, vw, qids, out1);
}

// Round 11
// 370.664 us; speedup vs baseline: 2.1825x; 1.0607x over previous
//
#include <hip/hip_runtime.h>

#define CC   256
#define HWS  4096
#define MPAD 4160   // 65*64, rows >= 4097 zero-padded
#define NB   4
#define NTIL 65

typedef __attribute__((ext_vector_type(8))) short   short8;
typedef __attribute__((ext_vector_type(4))) float   floatx4;

static __device__ __forceinline__ short8 ld8(const unsigned short* p) {
  return *(const short8*)p;
}
static __device__ __forceinline__ void st8(unsigned short* p, short8 v) {
  *(short8*)p = v;
}
static __device__ __forceinline__ unsigned short f2b(float x) {
  union { float f; unsigned u; } v; v.f = x;
  unsigned r = v.u + 0x7FFFu + ((v.u >> 16) & 1u);
  return (unsigned short)(r >> 16);
}
static __device__ __forceinline__ float b2f(unsigned short x) {
  union { unsigned u; float f; } v; v.u = ((unsigned)x) << 16;
  return v.f;
}

// ---- merged: St[d][c] = sim[c][d], Vw[d][c] = v_w[d][c] (bf16); colb biases
__global__ void prep_colb(const float* __restrict__ sim, const float* __restrict__ vw,
                          const float* __restrict__ mask,
                          unsigned short* __restrict__ St, unsigned short* __restrict__ Vw,
                          float* __restrict__ colb) {
  int blk = blockIdx.x, tid = threadIdx.x;
  if (blk < CC) {
    int dd = blk, c = tid;
    St[dd*CC + c] = f2b(sim[c*CC + dd]);
    Vw[dd*CC + c] = f2b(vw[dd*CC + c]);
    return;
  }
  int b = blk - CC;
  for (int m = tid; m < MPAD; m += 256) {
    float v;
    if (m < HWS)      v = (mask[b*HWS + m] - 1.0f) * 1e9f;
    else if (m == HWS) v = 0.0f;
    else               v = -3.0e38f;
    colb[b*MPAD + m] = v;
  }
}

// ---- Kt[b][m][d] = bf16(concat[b][d][m]); ALSO writes Kf fragment-major
__global__ void build_kt(const float* __restrict__ img, const float* __restrict__ exe,
                         unsigned short* __restrict__ Kt, unsigned short* __restrict__ Kf) {
  int b = blockIdx.x, mt = blockIdx.y, dt = blockIdx.z;
  int tid = threadIdx.x;
  int m0 = mt*64, d0 = dt*64;
  int w = tid >> 6, lane = tid & 63, lo = lane & 15, hi = lane >> 4;
  unsigned short* kft = Kf + (size_t)(b*NTIL + mt)*16384;
  if (mt == 64) {
    for (int i = 0; i < 16; ++i) {
      int m = m0 + (tid>>6) + i*4;
      int d = d0 + (tid&63);
      unsigned short v = 0;
      if (m == 4096) v = f2b(1.2f * exe[b*CC + d]);
      Kt[((size_t)b*MPAD + m)*CC + d] = v;
    }
#pragma unroll
    for (int ss = 0; ss < 2; ++ss) {
      int s = dt*8 + w*2 + ss;
      int k = s >> 2, t = s & 3;
      unsigned short tmp[8] = {0,0,0,0,0,0,0,0};
      if (t == 0 && lo == 0) {
#pragma unroll
        for (int j = 0; j < 8; ++j)
          tmp[j] = f2b(1.2f * exe[b*CC + k*32 + hi*8 + j]);
      }
      st8(kft + s*512 + lane*8, *(short8*)tmp);
    }
    return;
  }
  __shared__ float tile[64][65];
  for (int i = 0; i < 16; ++i) {
    int dl = (tid>>6) + i*4, ml = tid&63;
    tile[dl][ml] = img[((size_t)b*CC + d0+dl)*HWS + m0+ml];
  }
  __syncthreads();
  for (int i = 0; i < 16; ++i) {
    int ml = (tid>>6) + i*4, dl = tid&63;
    Kt[((size_t)b*MPAD + m0+ml)*CC + d0+dl] = f2b(tile[dl][ml]);
  }
#pragma unroll
  for (int ss = 0; ss < 2; ++ss) {
    int s = dt*8 + w*2 + ss;
    int k = s >> 2, t = s & 3;
    int ml = t*16 + lo;
    int dlb = (k - dt*2)*32 + hi*8;
    unsigned short tmp[8];
#pragma unroll
    for (int j = 0; j < 8; ++j) tmp[j] = f2b(tile[dlb + j][ml]);
    st8(kft + s*512 + lane*8, *(short8*)tmp);
  }
}

// ---- mode 0: Tb[b][n][d] = bf16( sum_c Kt[n][c]*St[d][c] )
// ---- mode 1: Vf fragment-major = bf16( sum_c Kt[m][c]*Vw[d][c] )
//      A-fragments read from Kf (same bytes as Kt rows, wave-contiguous 1KB
//      slots). Batched grid (b in blockIdx.x): round-10's 8-launch split cost
//      ~3us/launch in gaps.
__global__ __launch_bounds__(256) void gemm_small(const unsigned short* __restrict__ Kf,
    const unsigned short* __restrict__ Bm, unsigned short* __restrict__ Tout,
    unsigned short* __restrict__ Vf, int mode) {
  int b  = blockIdx.x;
  int by = blockIdx.y;
  int w  = threadIdx.x >> 6;
  int c0 = blockIdx.z*64;
  int lane = threadIdx.x & 63;
  int lo = lane & 15, hi = lane >> 4;
  __shared__ unsigned short lsh[64][72];
  floatx4 acc[4] = {};
  const unsigned short* kft = Kf + (size_t)(b*NTIL + by)*16384 + lane*8;
#pragma unroll
  for (int k = 0; k < 8; ++k) {
    short8 af = ld8(kft + (k*4 + w)*512);
#pragma unroll
    for (int t = 0; t < 4; ++t) {
      short8 bf = ld8(Bm + (size_t)(c0 + t*16 + lo)*CC + k*32 + hi*8);
      acc[t] = __builtin_amdgcn_mfma_f32_16x16x32_bf16(af, bf, acc[t], 0, 0, 0);
    }
  }
  if (mode == 0) {
#pragma unroll
    for (int t = 0; t < 4; ++t)
#pragma unroll
      for (int r = 0; r < 4; ++r)
        lsh[w*16 + hi*4 + r][t*16 + lo] = f2b(acc[t][r]);
    __syncthreads();
    int tid = threadIdx.x;
    int nl = tid >> 2, seg = tid & 3;
    unsigned short* dst = Tout + ((size_t)b*HWS + by*64 + nl)*CC + c0 + seg*16;
    st8(dst,     ld8(&lsh[nl][seg*16]));
    st8(dst + 8, ld8(&lsh[nl][seg*16 + 8]));
  } else {
#pragma unroll
    for (int t = 0; t < 4; ++t)
#pragma unroll
      for (int r = 0; r < 4; ++r)
        lsh[t*16 + lo][w*16 + hi*4 + r] = f2b(acc[t][r]);
    __syncthreads();
    unsigned short* vfb2 = Vf + (size_t)(b*NTIL + by)*16384;
#pragma unroll
    for (int ss = 0; ss < 2; ++ss) {
      int idx = w*2 + ss;            // [0,8)
      int h = idx >> 2, t4 = idx & 3;
      int s = h*16 + (c0 >> 4) + t4;
      short8 v = ld8(&lsh[t4*16 + (lane & 15)][h*32 + (lane >> 4)*8]);
      st8(vfb2 + s*512 + lane*8, v);
    }
  }
}

// ---- score mimicry of np/BLAS fp32 T-path, sequential FMA everywhere.
__global__ __launch_bounds__(256) void scores_kernel(const float* __restrict__ img,
    const float* __restrict__ sim, const float* __restrict__ exe,
    float* __restrict__ score32) {
  int b = blockIdx.x, n0 = blockIdx.y*32;
  int d = threadIdx.x;
  __shared__ float U[32][257];        // U[nl][c] = img[b, c, n0+nl]
  __shared__ float R[32][257];        // T32[nl][d]
  __shared__ float E[256];
  for (int idx = threadIdx.x; idx < 32*256; idx += 256) {
    int nl = idx & 31, c = idx >> 5;
    U[nl][c] = img[((size_t)b*CC + c)*HWS + n0 + nl];
  }
  E[d] = 1.2f * exe[b*CC + d];
  __syncthreads();
  float acc[32];
#pragma unroll
  for (int nl = 0; nl < 32; ++nl) acc[nl] = 0.f;
  for (int c = 0; c < CC; ++c) {
    float s_cd = sim[c*CC + d];
#pragma unroll
    for (int nl = 0; nl < 32; ++nl) acc[nl] = fmaf(U[nl][c], s_cd, acc[nl]);
  }
#pragma unroll
  for (int nl = 0; nl < 32; ++nl) R[nl][d] = acc[nl];
  __syncthreads();
  if (d < 32) {
    float s = 0.f;
    for (int dd = 0; dd < CC; ++dd) s = fmaf(R[d][dd], E[dd], s);
    score32[b*HWS + n0 + d] = s;
  }
}

// ---- top-150 via exact radix-select on distinct 44-bit keys + bitonic-256 sort.
__global__ __launch_bounds__(64) void select_kernel(const float* __restrict__ scores,
                                                    int* __restrict__ qids) {
  int b = blockIdx.x, lane = threadIdx.x;
  __shared__ float sc[HWS];
  __shared__ unsigned long long kx[HWS];
  __shared__ unsigned long long list[256];
  __shared__ unsigned int hist[256];
  __shared__ unsigned int st[4];
  __shared__ unsigned long long sh_base;

  const floatx4* s4 = (const floatx4*)(scores + (size_t)b*HWS);
  floatx4* c4 = (floatx4*)sc;
#pragma unroll
  for (int i = 0; i < 16; ++i) c4[i*64 + lane] = s4[i*64 + lane];
  __syncthreads();

  for (int i = 0; i < 64; ++i) {
    int idx = i*64 + lane;
    int y = i, x = lane;
    float c0 = sc[idx];
    float v = c0;
    if (y >= 1 && y <= 62 && x >= 1 && x <= 62) {
      bool ismax = (c0 > sc[idx-64]) && (c0 >= sc[idx+64]) &&
                   (c0 > sc[idx-1])  && (c0 >= sc[idx+1]);
      if (!ismax) v = c0 - 1e9f;
    }
    unsigned u = __float_as_uint(v);
    u = (u & 0x80000000u) ? ~u : (u | 0x80000000u);
    kx[idx] = (((unsigned long long)u) << 12) | (unsigned long long)(4095 - idx);
  }
  __syncthreads();

  unsigned long long base = 0;
  unsigned int need = 150, C = 0;
  for (int s = 36; s >= 4; s -= 8) {
    for (int i = lane; i < 256; i += 64) hist[i] = 0;
    __syncthreads();
    unsigned long long pref = base >> (s + 8);
    for (int i = 0; i < 64; ++i) {
      unsigned long long k = kx[i*64 + lane];
      if ((k >> (s + 8)) == pref) atomicAdd(&hist[(unsigned)(k >> s) & 255u], 1u);
    }
    __syncthreads();
    if (lane == 0) {
      unsigned cum = 0; int B = 0;
      for (int bin = 255; bin >= 0; --bin) {
        cum += hist[bin];
        if (cum >= need) { B = bin; break; }
      }
      st[0] = (150u - need) + cum;
      st[1] = need - (cum - hist[B]);
      sh_base = base | ((unsigned long long)B << s);
    }
    __syncthreads();
    C = st[0]; need = st[1]; base = sh_base;
    if (C <= 256u) break;
  }

  if (lane == 0) st[2] = 0;
  __syncthreads();
  for (int i = 0; i < 64; ++i) {
    unsigned long long k = kx[i*64 + lane];
    if (k >= base) {
      unsigned p = atomicAdd(&st[2], 1u);
      list[p] = k;
    }
  }
  __syncthreads();
  for (int i = lane; i < 256; i += 64) if (i >= (int)C) list[i] = 0ull;
  __syncthreads();

  for (int kk = 2; kk <= 256; kk <<= 1) {
    for (int j = kk >> 1; j > 0; j >>= 1) {
#pragma unroll
      for (int tt = 0; tt < 2; ++tt) {
        int t = lane + tt*64;
        int i2 = ((t & ~(j - 1)) << 1) | (t & (j - 1));
        int p2 = i2 | j;
        bool desc = ((i2 & kk) == 0);
        unsigned long long a = list[i2], c = list[p2];
        bool sw = desc ? (a < c) : (a > c);
        if (sw) { list[i2] = c; list[p2] = a; }
      }
      __syncthreads();
    }
  }

  for (int q = lane; q < 150; q += 64)
    qids[b*150 + q] = 4095 - (int)(list[q] & 0xFFFull);
}

// ---- fused flash attention v9 (FROZEN: proven 116us x4; occupancy ceiling is
//      1 wave/SIMD — real footprint ~400 of 512 unified regs/wave).
//      Dual 16-row groups per wave + KV-half split + quarter-phase X/Y
//      register streaming + fixed-max softmax.
__global__ __launch_bounds__(256, 1) void flash_kernel(
    const unsigned short* __restrict__ Tb, const unsigned short* __restrict__ Kt,
    const unsigned short* __restrict__ Kf, const unsigned short* __restrict__ Vf,
    const float* __restrict__ mask, const float* __restrict__ colb,
    float* __restrict__ acc0, float* __restrict__ accH, float* __restrict__ lsums) {
  int blk = blockIdx.x;                       // 256 blocks
  int b    = (blk & 7) >> 1;                  // batch pinned to XCD pair
  int half = blk & 1;                         // KV half pinned to XCD
  int g    = blk >> 3;                        // row-group-128 [0,32)
  int tid = threadIdx.x;
  int wave = tid >> 6, lane = tid & 63;
  int lo = lane & 15, hi = lane >> 4;
  int n0 = g*128 + wave*32;                   // this wave's 32 Q-rows
  int t0 = half ? 33 : 0, t1 = half ? NTIL : 33;

  __shared__ unsigned short pbuf[4][1152];    // per-wave P / M-exchange
  unsigned short* plw = &pbuf[wave][0];

  // Q fragments for this wave's two row-groups
  short8 q0[8], q1[8];
  const unsigned short* tb0 = Tb + ((size_t)b*HWS + n0 + lo)*CC + hi*8;
#pragma unroll
  for (int k = 0; k < 8; ++k) { q0[k] = ld8(tb0 + k*32); q1[k] = ld8(tb0 + 16*CC + k*32); }

  const unsigned short* kfb = Kf + (size_t)b*NTIL*16384 + lane*8;
  const unsigned short* vfb = Vf + (size_t)b*NTIL*16384 + lane*8;

  // prologue staging: kaA(t0) -> X, kaB(t0) -> Y (overlaps prologue dots)
  short8 X[16], Y[16];
#pragma unroll
  for (int i = 0; i < 16; ++i) X[i] = ld8(kfb + (size_t)t0*16384 + i*512);
#pragma unroll
  for (int i = 0; i < 16; ++i) Y[i] = ld8(kfb + (size_t)t0*16384 + (16 + i)*512);

  const float* mk = mask + b*HWS;

  // ---- prologue: diag and exe dots (fp32), fixed row max M = pick + 2
  float crb0[4], Msub0[4], crb1[4], Msub1[4];
  {
    const unsigned short* kep = Kt + ((size_t)b*MPAD + HWS)*CC + hi*8;
    // row-group 0
    float ddot = 0.f, edot = 0.f;
    const unsigned short* kdp = Kt + ((size_t)b*MPAD + n0 + lo)*CC + hi*8;
#pragma unroll
    for (int k = 0; k < 8; ++k) {
      short8 kd = ld8(kdp + k*32);
      short8 ke = ld8(kep + k*32);
#pragma unroll
      for (int j = 0; j < 8; ++j) {
        float qf = b2f((unsigned short)q0[k][j]);
        ddot = fmaf(qf, b2f((unsigned short)kd[j]), ddot);
        edot = fmaf(qf, b2f((unsigned short)ke[j]), edot);
      }
    }
    ddot += __shfl_xor(ddot, 16); ddot += __shfl_xor(ddot, 32);
    edot += __shfl_xor(edot, 16); edot += __shfl_xor(edot, 32);
    float Mrow = ((mk[n0 + lo] == 1.0f) ? ddot : edot) + 2.0f;
    float* fM = (float*)plw;
    fM[lo] = Mrow;
#pragma unroll
    for (int r = 0; r < 4; ++r) {
      Msub0[r] = fM[hi*4 + r];
      crb0[r]  = (mk[n0 + hi*4 + r] - 1.0f)*1e9f - Msub0[r];
    }
    // row-group 1
    ddot = 0.f; edot = 0.f;
    const unsigned short* kdp1 = Kt + ((size_t)b*MPAD + n0 + 16 + lo)*CC + hi*8;
#pragma unroll
    for (int k = 0; k < 8; ++k) {
      short8 kd = ld8(kdp1 + k*32);
      short8 ke = ld8(kep + k*32);
#pragma unroll
      for (int j = 0; j < 8; ++j) {
        float qf = b2f((unsigned short)q1[k][j]);
        ddot = fmaf(qf, b2f((unsigned short)kd[j]), ddot);
        edot = fmaf(qf, b2f((unsigned short)ke[j]), edot);
      }
    }
    ddot += __shfl_xor(ddot, 16); ddot += __shfl_xor(ddot, 32);
    edot += __shfl_xor(edot, 16); edot += __shfl_xor(edot, 32);
    float Mrow1 = ((mk[n0 + 16 + lo] == 1.0f) ? ddot : edot) + 2.0f;
    fM[lo] = Mrow1;
#pragma unroll
    for (int r = 0; r < 4; ++r) {
      Msub1[r] = fM[hi*4 + r];
      crb1[r]  = (mk[n0 + 16 + hi*4 + r] - 1.0f)*1e9f - Msub1[r];
    }
  }

  float lsum0[4] = {0.f, 0.f, 0.f, 0.f};
  float lsum1[4] = {0.f, 0.f, 0.f, 0.f};
  floatx4 o0[16] = {};
  floatx4 o1[16] = {};
  const float* cbb = colb + b*MPAD;

  for (int mt = t0; mt < t1; ++mt) {
    int m0 = mt*64;
    const unsigned short* vs = vfb + (size_t)mt*16384;
    // ---- QK-A: K slots 0..15 (k=0..3) from X; each fragment feeds both groups
    floatx4 s0[4] = {}, s1[4] = {};
#pragma unroll
    for (int k = 0; k < 4; ++k)
#pragma unroll
      for (int t = 0; t < 4; ++t) {
        s0[t] = __builtin_amdgcn_mfma_f32_16x16x32_bf16(q0[k], X[k*4 + t], s0[t], 0, 0, 0);
        s1[t] = __builtin_amdgcn_mfma_f32_16x16x32_bf16(q1[k], X[k*4 + t], s1[t], 0, 0, 0);
      }
    // issue vaA(mt) -> X (X dead after QK-A)
#pragma unroll
    for (int i = 0; i < 16; ++i) X[i] = ld8(vs + i*512);
    // ---- QK-B: K slots 16..31 (k=4..7) from Y
#pragma unroll
    for (int k = 4; k < 8; ++k)
#pragma unroll
      for (int t = 0; t < 4; ++t) {
        s0[t] = __builtin_amdgcn_mfma_f32_16x16x32_bf16(q0[k], Y[(k-4)*4 + t], s0[t], 0, 0, 0);
        s1[t] = __builtin_amdgcn_mfma_f32_16x16x32_bf16(q1[k], Y[(k-4)*4 + t], s1[t], 0, 0, 0);
      }
    // issue vaB(mt) -> Y (Y dead after QK-B)
#pragma unroll
    for (int i = 0; i < 16; ++i) Y[i] = ld8(vs + (16 + i)*512);
    // ---- fixed-max softmax: p = exp(s + colb[m] + rowb[r] - M_r)
    float cb[4];
#pragma unroll
    for (int t = 0; t < 4; ++t) cb[t] = cbb[m0 + t*16 + lo];
    short8 pf00, pf01, pf10, pf11;
    { // row-group 0
      float pr[4][4];
#pragma unroll
      for (int t = 0; t < 4; ++t)
#pragma unroll
        for (int r = 0; r < 4; ++r)
          pr[t][r] = s0[t][r] + cb[t] + crb0[r];
      if (mt == NTIL-1 && lo == 0) {
        // exe column (m==4096, t==0): never row-masked -> drop rowb
#pragma unroll
        for (int r = 0; r < 4; ++r) pr[0][r] = s0[0][r] - Msub0[r];
      }
#pragma unroll
      for (int t = 0; t < 4; ++t)
#pragma unroll
        for (int r = 0; r < 4; ++r) {
          float p = __expf(pr[t][r]);
          lsum0[r] += p;
          plw[(hi*4 + r)*72 + t*16 + lo] = f2b(p);
        }
      pf00 = *(const short8*)&plw[lo*72 + hi*8];
      pf01 = *(const short8*)&plw[lo*72 + 32 + hi*8];
    }
    { // row-group 1
      float pr[4][4];
#pragma unroll
      for (int t = 0; t < 4; ++t)
#pragma unroll
        for (int r = 0; r < 4; ++r)
          pr[t][r] = s1[t][r] + cb[t] + crb1[r];
      if (mt == NTIL-1 && lo == 0) {
#pragma unroll
        for (int r = 0; r < 4; ++r) pr[0][r] = s1[0][r] - Msub1[r];
      }
#pragma unroll
      for (int t = 0; t < 4; ++t)
#pragma unroll
        for (int r = 0; r < 4; ++r) {
          float p = __expf(pr[t][r]);
          lsum1[r] += p;
          plw[(hi*4 + r)*72 + t*16 + lo] = f2b(p);
        }
      pf10 = *(const short8*)&plw[lo*72 + hi*8];
      pf11 = *(const short8*)&plw[lo*72 + 32 + hi*8];
    }
    // ---- PV-A: V slots 0..15 (m 0..31) from X
#pragma unroll
    for (int sl = 0; sl < 16; ++sl) {
      o0[sl] = __builtin_amdgcn_mfma_f32_16x16x32_bf16(pf00, X[sl], o0[sl], 0, 0, 0);
      o1[sl] = __builtin_amdgcn_mfma_f32_16x16x32_bf16(pf10, X[sl], o1[sl], 0, 0, 0);
    }
    // issue kaA(mt+1) -> X
    if (mt + 1 < t1) {
      const unsigned short* ks = kfb + (size_t)(mt+1)*16384;
#pragma unroll
      for (int i = 0; i < 16; ++i) X[i] = ld8(ks + i*512);
    }
    // ---- PV-B: V slots 16..31 (m 32..63) from Y
#pragma unroll
    for (int sl = 0; sl < 16; ++sl) {
      o0[sl] = __builtin_amdgcn_mfma_f32_16x16x32_bf16(pf01, Y[sl], o0[sl], 0, 0, 0);
      o1[sl] = __builtin_amdgcn_mfma_f32_16x16x32_bf16(pf11, Y[sl], o1[sl], 0, 0, 0);
    }
    // issue kaB(mt+1) -> Y
    if (mt + 1 < t1) {
      const unsigned short* ks = kfb + (size_t)(mt+1)*16384;
#pragma unroll
      for (int i = 0; i < 16; ++i) Y[i] = ld8(ks + (16 + i)*512);
    }
  }
  // ---- l reduction over the 16 lo lanes (both groups)
#pragma unroll
  for (int r = 0; r < 4; ++r) {
#pragma unroll
    for (int off = 1; off < 16; off <<= 1) {
      lsum0[r] += __shfl_xor(lsum0[r], off);
      lsum1[r] += __shfl_xor(lsum1[r], off);
    }
  }
  // ---- epilogue: scatter fp32 UNNORMALIZED partials (no rounding here)
  float* op = (half ? accH : acc0) + (size_t)b*CC*HWS;
#pragma unroll
  for (int t = 0; t < 16; ++t)
#pragma unroll
    for (int r = 0; r < 4; ++r) {
      op[(size_t)(t*16 + lo)*HWS + n0 + hi*4 + r]      = o0[t][r];
      op[(size_t)(t*16 + lo)*HWS + n0 + 16 + hi*4 + r] = o1[t][r];
    }
  if (lo == 0) {
    float* lp = lsums + ((size_t)(half*NB + b))*HWS;
#pragma unroll
    for (int r = 0; r < 4; ++r) {
      lp[n0 + hi*4 + r]      = lsum0[r];
      lp[n0 + 16 + hi*4 + r] = lsum1[r];
    }
  }
}

// ---- out0[b][d][n] = bf16_round( (p0+p1) * 1/(l0+l1) ) + img  (coalesced)
__global__ __launch_bounds__(256) void finalize_kernel(const float* __restrict__ accH,
    const float* __restrict__ lsums, const float* __restrict__ img,
    float* __restrict__ out0) {
  int b = blockIdx.x >> 8;
  int d = blockIdx.x & 255;
  size_t base = ((size_t)b*CC + d)*HWS;
  const float* l0 = lsums + (size_t)b*HWS;
  const float* l1 = lsums + (size_t)(NB + b)*HWS;
  for (int n = threadIdx.x; n < HWS; n += 256) {
    float inv = 1.0f / (l0[n] + l1[n]);
    float o = (out0[base + n] + accH[base + n]) * inv;
    out0[base + n] = b2f(f2b(o)) + img[base + n];
  }
}

// ---- queries[b][q][d] = sum_c img[b][c][id]*v_w[d][c]  (fp32 seq FMA)
__global__ __launch_bounds__(256) void gather_kernel(const float* __restrict__ img,
    const float* __restrict__ vw, const int* __restrict__ qids, float* __restrict__ out1) {
  int blk = blockIdx.x;
  int b = blk / 150, q = blk % 150;
  int dd = threadIdx.x;
  __shared__ float col[CC];
  int id = qids[b*150 + q];
  col[dd] = img[((size_t)b*CC + dd)*HWS + id];
  __syncthreads();
  const float* vr = vw + dd*CC;
  float acc = 0.f;
  for (int c = 0; c < CC; ++c) acc = fmaf(col[c], vr[c], acc);
  out1[((size_t)(b*150 + q))*CC + dd] = acc;
}

extern "C" void kernel_launch(void* const* d_in, const int* in_sizes, int n_in,
                              void* d_out, int out_size, void* d_ws, size_t ws_size,
                              hipStream_t stream) {
  const float* img  = (const float*)d_in[0];
  const float* exe  = (const float*)d_in[1];
  const float* mask = (const float*)d_in[2];
  const float* sim  = (const float*)d_in[3];
  const float* vw   = (const float*)d_in[4];
  float* out0 = (float*)d_out;
  float* out1 = out0 + (size_t)NB*CC*HWS;

  char* ws = (char*)d_ws;
  size_t o = 0;
  unsigned short* Kt  = (unsigned short*)(ws + o); o += (size_t)NB*MPAD*CC*2;
  unsigned short* Tb  = (unsigned short*)(ws + o); o += (size_t)NB*HWS*CC*2;
  unsigned short* Kf  = (unsigned short*)(ws + o); o += (size_t)NB*NTIL*16384*2;
  unsigned short* Vf  = (unsigned short*)(ws + o); o += (size_t)NB*NTIL*16384*2;
  unsigned short* St  = (unsigned short*)(ws + o); o += (size_t)CC*CC*2;
  unsigned short* Vw  = (unsigned short*)(ws + o); o += (size_t)CC*CC*2;
  float*          scores = (float*)(ws + o);       o += (size_t)NB*HWS*4;
  float*          colb   = (float*)(ws + o);       o += (size_t)NB*MPAD*4;
  int*            qids   = (int*)(ws + o);         o += (size_t)NB*150*4;
  float*          accH   = (float*)(ws + o);       o += (size_t)NB*CC*HWS*4;
  float*          lsums  = (float*)(ws + o);       o += (size_t)2*NB*HWS*4;

  prep_colb  <<<dim3(CC + NB),    dim3(256), 0, stream>>>(sim, vw, mask, St, Vw, colb);
  build_kt   <<<dim3(NB, 65, 4),  dim3(256), 0, stream>>>(img, exe, Kt, Kf);
  gemm_small <<<dim3(NB, 64, 4),  dim3(256), 0, stream>>>(Kf, St, Tb, nullptr, 0);
  gemm_small <<<dim3(NB, 65, 4),  dim3(256), 0, stream>>>(Kf, Vw, nullptr, Vf, 1);
  scores_kernel<<<dim3(NB, 128),  dim3(256), 0, stream>>>(img, sim, exe, scores);
  select_kernel<<<dim3(NB),       dim3(64),  0, stream>>>(scores, qids);
  flash_kernel <<<dim3(256),      dim3(256), 0, stream>>>(Tb, Kt, Kf, Vf, mask, colb,
                                                          out0, accH, lsums);
  finalize_kernel<<<dim3(NB*CC),  dim3(256), 0, stream>>>(accH, lsums, img, out0);
  gather_kernel<<<dim3(NB*150),   dim3(256), 0, stream>>>(img, vw, qids, out1);
}

// Round 12
// 357.018 us; speedup vs baseline: 2.2659x; 1.0382x over previous
//
#include <hip/hip_runtime.h>

#define CC   256
#define HWS  4096
#define MPAD 4160   // 65*64, rows >= 4097 zero-padded
#define NB   4
#define NTIL 65

typedef __attribute__((ext_vector_type(8))) short   short8;
typedef __attribute__((ext_vector_type(4))) float   floatx4;

static __device__ __forceinline__ short8 ld8(const unsigned short* p) {
  return *(const short8*)p;
}
static __device__ __forceinline__ void st8(unsigned short* p, short8 v) {
  *(short8*)p = v;
}
static __device__ __forceinline__ unsigned short f2b(float x) {
  union { float f; unsigned u; } v; v.f = x;
  unsigned r = v.u + 0x7FFFu + ((v.u >> 16) & 1u);
  return (unsigned short)(r >> 16);
}
static __device__ __forceinline__ float b2f(unsigned short x) {
  union { unsigned u; float f; } v; v.u = ((unsigned)x) << 16;
  return v.f;
}

// ---- build_kt v2: writes ONLY Kf (fragment-major). Kt is eliminated — its
//      sole remaining consumer (flash prologue) reads the identical bytes from
//      Kf at better coalescing. Extra grid slice b==NB runs the old prep_colb
//      (260 blocks = CC + NB exactly): St/Vw transposes + colb biases.
__global__ void build_kt(const float* __restrict__ img, const float* __restrict__ exe,
                         const float* __restrict__ sim, const float* __restrict__ vw,
                         const float* __restrict__ mask,
                         unsigned short* __restrict__ Kf, unsigned short* __restrict__ St,
                         unsigned short* __restrict__ Vw, float* __restrict__ colb) {
  int b = blockIdx.x, mt = blockIdx.y, dt = blockIdx.z;
  int tid = threadIdx.x;
  if (b == NB) {                       // merged prep_colb slice
    int pblk = mt*4 + dt;              // [0, 260) = CC + NB
    if (pblk < CC) {
      St[pblk*CC + tid] = f2b(sim[tid*CC + pblk]);
      Vw[pblk*CC + tid] = f2b(vw[pblk*CC + tid]);
      return;
    }
    int bb = pblk - CC;
    for (int m = tid; m < MPAD; m += 256) {
      float v;
      if (m < HWS)      v = (mask[bb*HWS + m] - 1.0f) * 1e9f;
      else if (m == HWS) v = 0.0f;
      else               v = -3.0e38f;
      colb[bb*MPAD + m] = v;
    }
    return;
  }
  int m0 = mt*64, d0 = dt*64;
  int w = tid >> 6, lane = tid & 63, lo = lane & 15, hi = lane >> 4;
  unsigned short* kft = Kf + (size_t)(b*NTIL + mt)*16384;
  if (mt == 64) {
#pragma unroll
    for (int ss = 0; ss < 2; ++ss) {
      int s = dt*8 + w*2 + ss;
      int k = s >> 2, t = s & 3;
      unsigned short tmp[8] = {0,0,0,0,0,0,0,0};
      if (t == 0 && lo == 0) {
#pragma unroll
        for (int j = 0; j < 8; ++j)
          tmp[j] = f2b(1.2f * exe[b*CC + k*32 + hi*8 + j]);
      }
      st8(kft + s*512 + lane*8, *(short8*)tmp);
    }
    return;
  }
  __shared__ float tile[64][65];
  for (int i = 0; i < 16; ++i) {
    int dl = (tid>>6) + i*4, ml = tid&63;
    tile[dl][ml] = img[((size_t)b*CC + d0+dl)*HWS + m0+ml];
  }
  __syncthreads();
#pragma unroll
  for (int ss = 0; ss < 2; ++ss) {
    int s = dt*8 + w*2 + ss;
    int k = s >> 2, t = s & 3;
    int ml = t*16 + lo;
    int dlb = (k - dt*2)*32 + hi*8;
    unsigned short tmp[8];
#pragma unroll
    for (int j = 0; j < 8; ++j) tmp[j] = f2b(tile[dlb + j][ml]);
    st8(kft + s*512 + lane*8, *(short8*)tmp);
  }
}

// ---- merged gemm: blockIdx.y in [0,129): y<64 -> mode0 (Tb), else mode1 (Vf).
//      A-fragments from Kf (wave-contiguous 1KB slots).
__global__ __launch_bounds__(256) void gemm_small(const unsigned short* __restrict__ Kf,
    const unsigned short* __restrict__ St, const unsigned short* __restrict__ Vwm,
    unsigned short* __restrict__ Tout, unsigned short* __restrict__ Vf) {
  int b   = blockIdx.x;
  int byr = blockIdx.y;
  int mode = (byr >= 64);
  int by  = mode ? byr - 64 : byr;
  int w   = threadIdx.x >> 6;
  int c0  = blockIdx.z*64;
  int lane = threadIdx.x & 63;
  int lo = lane & 15, hi = lane >> 4;
  const unsigned short* Bm = mode ? Vwm : St;
  __shared__ unsigned short lsh[64][72];
  floatx4 acc[4] = {};
  const unsigned short* kft = Kf + (size_t)(b*NTIL + by)*16384 + lane*8;
#pragma unroll
  for (int k = 0; k < 8; ++k) {
    short8 af = ld8(kft + (k*4 + w)*512);
#pragma unroll
    for (int t = 0; t < 4; ++t) {
      short8 bf = ld8(Bm + (size_t)(c0 + t*16 + lo)*CC + k*32 + hi*8);
      acc[t] = __builtin_amdgcn_mfma_f32_16x16x32_bf16(af, bf, acc[t], 0, 0, 0);
    }
  }
  if (!mode) {
#pragma unroll
    for (int t = 0; t < 4; ++t)
#pragma unroll
      for (int r = 0; r < 4; ++r)
        lsh[w*16 + hi*4 + r][t*16 + lo] = f2b(acc[t][r]);
    __syncthreads();
    int tid = threadIdx.x;
    int nl = tid >> 2, seg = tid & 3;
    unsigned short* dst = Tout + ((size_t)b*HWS + by*64 + nl)*CC + c0 + seg*16;
    st8(dst,     ld8(&lsh[nl][seg*16]));
    st8(dst + 8, ld8(&lsh[nl][seg*16 + 8]));
  } else {
#pragma unroll
    for (int t = 0; t < 4; ++t)
#pragma unroll
      for (int r = 0; r < 4; ++r)
        lsh[t*16 + lo][w*16 + hi*4 + r] = f2b(acc[t][r]);
    __syncthreads();
    unsigned short* vfb2 = Vf + (size_t)(b*NTIL + by)*16384;
#pragma unroll
    for (int ss = 0; ss < 2; ++ss) {
      int idx = w*2 + ss;            // [0,8)
      int h = idx >> 2, t4 = idx & 3;
      int s = h*16 + (c0 >> 4) + t4;
      short8 v = ld8(&lsh[t4*16 + (lane & 15)][h*32 + (lane >> 4)*8]);
      st8(vfb2 + s*512 + lane*8, v);
    }
  }
}

// ---- score mimicry of np/BLAS fp32 T-path, sequential FMA everywhere.
__global__ __launch_bounds__(256) void scores_kernel(const float* __restrict__ img,
    const float* __restrict__ sim, const float* __restrict__ exe,
    float* __restrict__ score32) {
  int b = blockIdx.x, n0 = blockIdx.y*32;
  int d = threadIdx.x;
  __shared__ float U[32][257];        // U[nl][c] = img[b, c, n0+nl]
  __shared__ float R[32][257];        // T32[nl][d]
  __shared__ float E[256];
  for (int idx = threadIdx.x; idx < 32*256; idx += 256) {
    int nl = idx & 31, c = idx >> 5;
    U[nl][c] = img[((size_t)b*CC + c)*HWS + n0 + nl];
  }
  E[d] = 1.2f * exe[b*CC + d];
  __syncthreads();
  float acc[32];
#pragma unroll
  for (int nl = 0; nl < 32; ++nl) acc[nl] = 0.f;
  for (int c = 0; c < CC; ++c) {
    float s_cd = sim[c*CC + d];
#pragma unroll
    for (int nl = 0; nl < 32; ++nl) acc[nl] = fmaf(U[nl][c], s_cd, acc[nl]);
  }
#pragma unroll
  for (int nl = 0; nl < 32; ++nl) R[nl][d] = acc[nl];
  __syncthreads();
  if (d < 32) {
    float s = 0.f;
    for (int dd = 0; dd < CC; ++dd) s = fmaf(R[d][dd], E[dd], s);
    score32[b*HWS + n0 + d] = s;
  }
}

// ---- top-150 via exact radix-select on distinct 44-bit keys + bitonic-256 sort.
__global__ __launch_bounds__(64) void select_kernel(const float* __restrict__ scores,
                                                    int* __restrict__ qids) {
  int b = blockIdx.x, lane = threadIdx.x;
  __shared__ float sc[HWS];
  __shared__ unsigned long long kx[HWS];
  __shared__ unsigned long long list[256];
  __shared__ unsigned int hist[256];
  __shared__ unsigned int st[4];
  __shared__ unsigned long long sh_base;

  const floatx4* s4 = (const floatx4*)(scores + (size_t)b*HWS);
  floatx4* c4 = (floatx4*)sc;
#pragma unroll
  for (int i = 0; i < 16; ++i) c4[i*64 + lane] = s4[i*64 + lane];
  __syncthreads();

  for (int i = 0; i < 64; ++i) {
    int idx = i*64 + lane;
    int y = i, x = lane;
    float c0 = sc[idx];
    float v = c0;
    if (y >= 1 && y <= 62 && x >= 1 && x <= 62) {
      bool ismax = (c0 > sc[idx-64]) && (c0 >= sc[idx+64]) &&
                   (c0 > sc[idx-1])  && (c0 >= sc[idx+1]);
      if (!ismax) v = c0 - 1e9f;
    }
    unsigned u = __float_as_uint(v);
    u = (u & 0x80000000u) ? ~u : (u | 0x80000000u);
    kx[idx] = (((unsigned long long)u) << 12) | (unsigned long long)(4095 - idx);
  }
  __syncthreads();

  unsigned long long base = 0;
  unsigned int need = 150, C = 0;
  for (int s = 36; s >= 4; s -= 8) {
    for (int i = lane; i < 256; i += 64) hist[i] = 0;
    __syncthreads();
    unsigned long long pref = base >> (s + 8);
    for (int i = 0; i < 64; ++i) {
      unsigned long long k = kx[i*64 + lane];
      if ((k >> (s + 8)) == pref) atomicAdd(&hist[(unsigned)(k >> s) & 255u], 1u);
    }
    __syncthreads();
    if (lane == 0) {
      unsigned cum = 0; int B = 0;
      for (int bin = 255; bin >= 0; --bin) {
        cum += hist[bin];
        if (cum >= need) { B = bin; break; }
      }
      st[0] = (150u - need) + cum;
      st[1] = need - (cum - hist[B]);
      sh_base = base | ((unsigned long long)B << s);
    }
    __syncthreads();
    C = st[0]; need = st[1]; base = sh_base;
    if (C <= 256u) break;
  }

  if (lane == 0) st[2] = 0;
  __syncthreads();
  for (int i = 0; i < 64; ++i) {
    unsigned long long k = kx[i*64 + lane];
    if (k >= base) {
      unsigned p = atomicAdd(&st[2], 1u);
      list[p] = k;
    }
  }
  __syncthreads();
  for (int i = lane; i < 256; i += 64) if (i >= (int)C) list[i] = 0ull;
  __syncthreads();

  for (int kk = 2; kk <= 256; kk <<= 1) {
    for (int j = kk >> 1; j > 0; j >>= 1) {
#pragma unroll
      for (int tt = 0; tt < 2; ++tt) {
        int t = lane + tt*64;
        int i2 = ((t & ~(j - 1)) << 1) | (t & (j - 1));
        int p2 = i2 | j;
        bool desc = ((i2 & kk) == 0);
        unsigned long long a = list[i2], c = list[p2];
        bool sw = desc ? (a < c) : (a > c);
        if (sw) { list[i2] = c; list[p2] = a; }
      }
      __syncthreads();
    }
  }

  for (int q = lane; q < 150; q += 64)
    qids[b*150 + q] = 4095 - (int)(list[q] & 0xFFFull);
}

// ---- fused flash attention v9 (FROZEN schedule, proven 116us x5). Prologue
//      now reads diag/exe rows from Kf (bit-identical bytes, wave-contiguous):
//      Kf[nt][(k*4+t16)*512 + lane*8] == Kt[(n0+lo)*CC + k*32+hi*8];
//      exe row: Kf tile 64, slot k*4, offset hi*128.
__global__ __launch_bounds__(256, 1) void flash_kernel(
    const unsigned short* __restrict__ Tb, const unsigned short* __restrict__ Kf,
    const unsigned short* __restrict__ Vf, const float* __restrict__ mask,
    const float* __restrict__ colb,
    float* __restrict__ acc0, float* __restrict__ accH, float* __restrict__ lsums) {
  int blk = blockIdx.x;                       // 256 blocks
  int b    = (blk & 7) >> 1;                  // batch pinned to XCD pair
  int half = blk & 1;                         // KV half pinned to XCD
  int g    = blk >> 3;                        // row-group-128 [0,32)
  int tid = threadIdx.x;
  int wave = tid >> 6, lane = tid & 63;
  int lo = lane & 15, hi = lane >> 4;
  int n0 = g*128 + wave*32;                   // this wave's 32 Q-rows
  int t0 = half ? 33 : 0, t1 = half ? NTIL : 33;

  __shared__ unsigned short pbuf[4][1152];    // per-wave P / M-exchange
  unsigned short* plw = &pbuf[wave][0];

  // Q fragments for this wave's two row-groups
  short8 q0[8], q1[8];
  const unsigned short* tb0 = Tb + ((size_t)b*HWS + n0 + lo)*CC + hi*8;
#pragma unroll
  for (int k = 0; k < 8; ++k) { q0[k] = ld8(tb0 + k*32); q1[k] = ld8(tb0 + 16*CC + k*32); }

  const unsigned short* kfb = Kf + (size_t)b*NTIL*16384 + lane*8;
  const unsigned short* vfb = Vf + (size_t)b*NTIL*16384 + lane*8;

  // prologue staging: kaA(t0) -> X, kaB(t0) -> Y (overlaps prologue dots)
  short8 X[16], Y[16];
#pragma unroll
  for (int i = 0; i < 16; ++i) X[i] = ld8(kfb + (size_t)t0*16384 + i*512);
#pragma unroll
  for (int i = 0; i < 16; ++i) Y[i] = ld8(kfb + (size_t)t0*16384 + (16 + i)*512);

  const float* mk = mask + b*HWS;

  // ---- prologue: diag and exe dots (fp32), fixed row max M = pick + 2
  float crb0[4], Msub0[4], crb1[4], Msub1[4];
  {
    int nt  = n0 >> 6;                        // 64-row tile of this wave's rows
    int t16 = (n0 & 63) >> 4;                 // 16-row group within tile
    const unsigned short* kfd = Kf + (size_t)(b*NTIL + nt)*16384 + lane*8;
    const unsigned short* kfe = Kf + (size_t)(b*NTIL + 64)*16384 + hi*128;
    // row-group 0
    float ddot = 0.f, edot = 0.f;
#pragma unroll
    for (int k = 0; k < 8; ++k) {
      short8 kd = ld8(kfd + (k*4 + t16)*512);
      short8 ke = ld8(kfe + (k*4)*512);
#pragma unroll
      for (int j = 0; j < 8; ++j) {
        float qf = b2f((unsigned short)q0[k][j]);
        ddot = fmaf(qf, b2f((unsigned short)kd[j]), ddot);
        edot = fmaf(qf, b2f((unsigned short)ke[j]), edot);
      }
    }
    ddot += __shfl_xor(ddot, 16); ddot += __shfl_xor(ddot, 32);
    edot += __shfl_xor(edot, 16); edot += __shfl_xor(edot, 32);
    float Mrow = ((mk[n0 + lo] == 1.0f) ? ddot : edot) + 2.0f;
    float* fM = (float*)plw;
    fM[lo] = Mrow;
#pragma unroll
    for (int r = 0; r < 4; ++r) {
      Msub0[r] = fM[hi*4 + r];
      crb0[r]  = (mk[n0 + hi*4 + r] - 1.0f)*1e9f - Msub0[r];
    }
    // row-group 1
    ddot = 0.f; edot = 0.f;
#pragma unroll
    for (int k = 0; k < 8; ++k) {
      short8 kd = ld8(kfd + (k*4 + t16 + 1)*512);
      short8 ke = ld8(kfe + (k*4)*512);
#pragma unroll
      for (int j = 0; j < 8; ++j) {
        float qf = b2f((unsigned short)q1[k][j]);
        ddot = fmaf(qf, b2f((unsigned short)kd[j]), ddot);
        edot = fmaf(qf, b2f((unsigned short)ke[j]), edot);
      }
    }
    ddot += __shfl_xor(ddot, 16); ddot += __shfl_xor(ddot, 32);
    edot += __shfl_xor(edot, 16); edot += __shfl_xor(edot, 32);
    float Mrow1 = ((mk[n0 + 16 + lo] == 1.0f) ? ddot : edot) + 2.0f;
    fM[lo] = Mrow1;
#pragma unroll
    for (int r = 0; r < 4; ++r) {
      Msub1[r] = fM[hi*4 + r];
      crb1[r]  = (mk[n0 + 16 + hi*4 + r] - 1.0f)*1e9f - Msub1[r];
    }
  }

  float lsum0[4] = {0.f, 0.f, 0.f, 0.f};
  float lsum1[4] = {0.f, 0.f, 0.f, 0.f};
  floatx4 o0[16] = {};
  floatx4 o1[16] = {};
  const float* cbb = colb + b*MPAD;

  for (int mt = t0; mt < t1; ++mt) {
    int m0 = mt*64;
    const unsigned short* vs = vfb + (size_t)mt*16384;
    // ---- QK-A: K slots 0..15 (k=0..3) from X; each fragment feeds both groups
    floatx4 s0[4] = {}, s1[4] = {};
#pragma unroll
    for (int k = 0; k < 4; ++k)
#pragma unroll
      for (int t = 0; t < 4; ++t) {
        s0[t] = __builtin_amdgcn_mfma_f32_16x16x32_bf16(q0[k], X[k*4 + t], s0[t], 0, 0, 0);
        s1[t] = __builtin_amdgcn_mfma_f32_16x16x32_bf16(q1[k], X[k*4 + t], s1[t], 0, 0, 0);
      }
    // issue vaA(mt) -> X (X dead after QK-A)
#pragma unroll
    for (int i = 0; i < 16; ++i) X[i] = ld8(vs + i*512);
    // ---- QK-B: K slots 16..31 (k=4..7) from Y
#pragma unroll
    for (int k = 4; k < 8; ++k)
#pragma unroll
      for (int t = 0; t < 4; ++t) {
        s0[t] = __builtin_amdgcn_mfma_f32_16x16x32_bf16(q0[k], Y[(k-4)*4 + t], s0[t], 0, 0, 0);
        s1[t] = __builtin_amdgcn_mfma_f32_16x16x32_bf16(q1[k], Y[(k-4)*4 + t], s1[t], 0, 0, 0);
      }
    // issue vaB(mt) -> Y (Y dead after QK-B)
#pragma unroll
    for (int i = 0; i < 16; ++i) Y[i] = ld8(vs + (16 + i)*512);
    // ---- fixed-max softmax: p = exp(s + colb[m] + rowb[r] - M_r)
    float cb[4];
#pragma unroll
    for (int t = 0; t < 4; ++t) cb[t] = cbb[m0 + t*16 + lo];
    short8 pf00, pf01, pf10, pf11;
    { // row-group 0
      float pr[4][4];
#pragma unroll
      for (int t = 0; t < 4; ++t)
#pragma unroll
        for (int r = 0; r < 4; ++r)
          pr[t][r] = s0[t][r] + cb[t] + crb0[r];
      if (mt == NTIL-1 && lo == 0) {
        // exe column (m==4096, t==0): never row-masked -> drop rowb
#pragma unroll
        for (int r = 0; r < 4; ++r) pr[0][r] = s0[0][r] - Msub0[r];
      }
#pragma unroll
      for (int t = 0; t < 4; ++t)
#pragma unroll
        for (int r = 0; r < 4; ++r) {
          float p = __expf(pr[t][r]);
          lsum0[r] += p;
          plw[(hi*4 + r)*72 + t*16 + lo] = f2b(p);
        }
      pf00 = *(const short8*)&plw[lo*72 + hi*8];
      pf01 = *(const short8*)&plw[lo*72 + 32 + hi*8];
    }
    { // row-group 1
      float pr[4][4];
#pragma unroll
      for (int t = 0; t < 4; ++t)
#pragma unroll
        for (int r = 0; r < 4; ++r)
          pr[t][r] = s1[t][r] + cb[t] + crb1[r];
      if (mt == NTIL-1 && lo == 0) {
#pragma unroll
        for (int r = 0; r < 4; ++r) pr[0][r] = s1[0][r] - Msub1[r];
      }
#pragma unroll
      for (int t = 0; t < 4; ++t)
#pragma unroll
        for (int r = 0; r < 4; ++r) {
          float p = __expf(pr[t][r]);
          lsum1[r] += p;
          plw[(hi*4 + r)*72 + t*16 + lo] = f2b(p);
        }
      pf10 = *(const short8*)&plw[lo*72 + hi*8];
      pf11 = *(const short8*)&plw[lo*72 + 32 + hi*8];
    }
    // ---- PV-A: V slots 0..15 (m 0..31) from X
#pragma unroll
    for (int sl = 0; sl < 16; ++sl) {
      o0[sl] = __builtin_amdgcn_mfma_f32_16x16x32_bf16(pf00, X[sl], o0[sl], 0, 0, 0);
      o1[sl] = __builtin_amdgcn_mfma_f32_16x16x32_bf16(pf10, X[sl], o1[sl], 0, 0, 0);
    }
    // issue kaA(mt+1) -> X
    if (mt + 1 < t1) {
      const unsigned short* ks = kfb + (size_t)(mt+1)*16384;
#pragma unroll
      for (int i = 0; i < 16; ++i) X[i] = ld8(ks + i*512);
    }
    // ---- PV-B: V slots 16..31 (m 32..63) from Y
#pragma unroll
    for (int sl = 0; sl < 16; ++sl) {
      o0[sl] = __builtin_amdgcn_mfma_f32_16x16x32_bf16(pf01, Y[sl], o0[sl], 0, 0, 0);
      o1[sl] = __builtin_amdgcn_mfma_f32_16x16x32_bf16(pf11, Y[sl], o1[sl], 0, 0, 0);
    }
    // issue kaB(mt+1) -> Y
    if (mt + 1 < t1) {
      const unsigned short* ks = kfb + (size_t)(mt+1)*16384;
#pragma unroll
      for (int i = 0; i < 16; ++i) Y[i] = ld8(ks + (16 + i)*512);
    }
  }
  // ---- l reduction over the 16 lo lanes (both groups)
#pragma unroll
  for (int r = 0; r < 4; ++r) {
#pragma unroll
    for (int off = 1; off < 16; off <<= 1) {
      lsum0[r] += __shfl_xor(lsum0[r], off);
      lsum1[r] += __shfl_xor(lsum1[r], off);
    }
  }
  // ---- epilogue: scatter fp32 UNNORMALIZED partials (no rounding here)
  float* op = (half ? accH : acc0) + (size_t)b*CC*HWS;
#pragma unroll
  for (int t = 0; t < 16; ++t)
#pragma unroll
    for (int r = 0; r < 4; ++r) {
      op[(size_t)(t*16 + lo)*HWS + n0 + hi*4 + r]      = o0[t][r];
      op[(size_t)(t*16 + lo)*HWS + n0 + 16 + hi*4 + r] = o1[t][r];
    }
  if (lo == 0) {
    float* lp = lsums + ((size_t)(half*NB + b))*HWS;
#pragma unroll
    for (int r = 0; r < 4; ++r) {
      lp[n0 + hi*4 + r]      = lsum0[r];
      lp[n0 + 16 + hi*4 + r] = lsum1[r];
    }
  }
}

// ---- merged finalize + gather (disjoint outputs; both ordered after
//      flash and select). blk < NB*CC: finalize; else gather.
__global__ __launch_bounds__(256) void fin_gather(const float* __restrict__ accH,
    const float* __restrict__ lsums, const float* __restrict__ img,
    const float* __restrict__ vw, const int* __restrict__ qids,
    float* __restrict__ out0, float* __restrict__ out1) {
  int blk = blockIdx.x;
  if (blk < NB*CC) {
    int b = blk >> 8;
    int d = blk & 255;
    size_t base = ((size_t)b*CC + d)*HWS;
    const float* l0 = lsums + (size_t)b*HWS;
    const float* l1 = lsums + (size_t)(NB + b)*HWS;
    for (int n = threadIdx.x; n < HWS; n += 256) {
      float inv = 1.0f / (l0[n] + l1[n]);
      float o = (out0[base + n] + accH[base + n]) * inv;
      out0[base + n] = b2f(f2b(o)) + img[base + n];
    }
    return;
  }
  int gb = blk - NB*CC;
  int b = gb / 150, q = gb % 150;
  int dd = threadIdx.x;
  __shared__ float col[CC];
  int id = qids[b*150 + q];
  col[dd] = img[((size_t)b*CC + dd)*HWS + id];
  __syncthreads();
  const float* vr = vw + dd*CC;
  float acc = 0.f;
  for (int c = 0; c < CC; ++c) acc = fmaf(col[c], vr[c], acc);
  out1[((size_t)(b*150 + q))*CC + dd] = acc;
}

extern "C" void kernel_launch(void* const* d_in, const int* in_sizes, int n_in,
                              void* d_out, int out_size, void* d_ws, size_t ws_size,
                              hipStream_t stream) {
  const float* img  = (const float*)d_in[0];
  const float* exe  = (const float*)d_in[1];
  const float* mask = (const float*)d_in[2];
  const float* sim  = (const float*)d_in[3];
  const float* vw   = (const float*)d_in[4];
  float* out0 = (float*)d_out;
  float* out1 = out0 + (size_t)NB*CC*HWS;

  char* ws = (char*)d_ws;
  size_t o = 0;
  unsigned short* Tb  = (unsigned short*)(ws + o); o += (size_t)NB*HWS*CC*2;
  unsigned short* Kf  = (unsigned short*)(ws + o); o += (size_t)NB*NTIL*16384*2;
  unsigned short* Vf  = (unsigned short*)(ws + o); o += (size_t)NB*NTIL*16384*2;
  unsigned short* St  = (unsigned short*)(ws + o); o += (size_t)CC*CC*2;
  unsigned short* Vw  = (unsigned short*)(ws + o); o += (size_t)CC*CC*2;
  float*          scores = (float*)(ws + o);       o += (size_t)NB*HWS*4;
  float*          colb   = (float*)(ws + o);       o += (size_t)NB*MPAD*4;
  int*            qids   = (int*)(ws + o);         o += (size_t)NB*150*4;
  float*          accH   = (float*)(ws + o);       o += (size_t)NB*CC*HWS*4;
  float*          lsums  = (float*)(ws + o);       o += (size_t)2*NB*HWS*4;

  build_kt   <<<dim3(NB+1, 65, 4), dim3(256), 0, stream>>>(img, exe, sim, vw, mask,
                                                           Kf, St, Vw, colb);
  gemm_small <<<dim3(NB, 129, 4),  dim3(256), 0, stream>>>(Kf, St, Vw, Tb, Vf);
  scores_kernel<<<dim3(NB, 128),   dim3(256), 0, stream>>>(img, sim, exe, scores);
  select_kernel<<<dim3(NB),        dim3(64),  0, stream>>>(scores, qids);
  flash_kernel <<<dim3(256),       dim3(256), 0, stream>>>(Tb, Kf, Vf, mask, colb,
                                                           out0, accH, lsums);
  fin_gather   <<<dim3(NB*CC + NB*150), dim3(256), 0, stream>>>(accH, lsums, img, vw,
                                                                qids, out0, out1);
}

// Round 13
// 333.018 us; speedup vs baseline: 2.4292x; 1.0721x over previous
//
#include <hip/hip_runtime.h>

#define CC   256
#define HWS  4096
#define MPAD 4160   // 65*64, rows >= 4097 zero-padded
#define NB   4
#define NTIL 65

typedef __attribute__((ext_vector_type(8))) short   short8;
typedef __attribute__((ext_vector_type(4))) float   floatx4;

static __device__ __forceinline__ short8 ld8(const unsigned short* p) {
  return *(const short8*)p;
}
static __device__ __forceinline__ void st8(unsigned short* p, short8 v) {
  *(short8*)p = v;
}
static __device__ __forceinline__ unsigned short f2b(float x) {
  union { float f; unsigned u; } v; v.f = x;
  unsigned r = v.u + 0x7FFFu + ((v.u >> 16) & 1u);
  return (unsigned short)(r >> 16);
}
static __device__ __forceinline__ float b2f(unsigned short x) {
  union { unsigned u; float f; } v; v.u = ((unsigned)x) << 16;
  return v.f;
}

// ---- build_kt v2: writes ONLY Kf (fragment-major). Extra grid slice b==NB
//      runs the old prep_colb (260 blocks = CC + NB): St/Vw transposes + colb.
__global__ void build_kt(const float* __restrict__ img, const float* __restrict__ exe,
                         const float* __restrict__ sim, const float* __restrict__ vw,
                         const float* __restrict__ mask,
                         unsigned short* __restrict__ Kf, unsigned short* __restrict__ St,
                         unsigned short* __restrict__ Vw, float* __restrict__ colb) {
  int b = blockIdx.x, mt = blockIdx.y, dt = blockIdx.z;
  int tid = threadIdx.x;
  if (b == NB) {                       // merged prep_colb slice
    int pblk = mt*4 + dt;              // [0, 260) = CC + NB
    if (pblk < CC) {
      St[pblk*CC + tid] = f2b(sim[tid*CC + pblk]);
      Vw[pblk*CC + tid] = f2b(vw[pblk*CC + tid]);
      return;
    }
    int bb = pblk - CC;
    for (int m = tid; m < MPAD; m += 256) {
      float v;
      if (m < HWS)      v = (mask[bb*HWS + m] - 1.0f) * 1e9f;
      else if (m == HWS) v = 0.0f;
      else               v = -3.0e38f;
      colb[bb*MPAD + m] = v;
    }
    return;
  }
  int m0 = mt*64, d0 = dt*64;
  int w = tid >> 6, lane = tid & 63, lo = lane & 15, hi = lane >> 4;
  unsigned short* kft = Kf + (size_t)(b*NTIL + mt)*16384;
  if (mt == 64) {
#pragma unroll
    for (int ss = 0; ss < 2; ++ss) {
      int s = dt*8 + w*2 + ss;
      int k = s >> 2, t = s & 3;
      unsigned short tmp[8] = {0,0,0,0,0,0,0,0};
      if (t == 0 && lo == 0) {
#pragma unroll
        for (int j = 0; j < 8; ++j)
          tmp[j] = f2b(1.2f * exe[b*CC + k*32 + hi*8 + j]);
      }
      st8(kft + s*512 + lane*8, *(short8*)tmp);
    }
    return;
  }
  __shared__ float tile[64][65];
  for (int i = 0; i < 16; ++i) {
    int dl = (tid>>6) + i*4, ml = tid&63;
    tile[dl][ml] = img[((size_t)b*CC + d0+dl)*HWS + m0+ml];
  }
  __syncthreads();
#pragma unroll
  for (int ss = 0; ss < 2; ++ss) {
    int s = dt*8 + w*2 + ss;
    int k = s >> 2, t = s & 3;
    int ml = t*16 + lo;
    int dlb = (k - dt*2)*32 + hi*8;
    unsigned short tmp[8];
#pragma unroll
    for (int j = 0; j < 8; ++j) tmp[j] = f2b(tile[dlb + j][ml]);
    st8(kft + s*512 + lane*8, *(short8*)tmp);
  }
}

// ---- merged gemm: blockIdx.y in [0,129): y<64 -> mode0 (Tb), else mode1 (Vf).
__global__ __launch_bounds__(256) void gemm_small(const unsigned short* __restrict__ Kf,
    const unsigned short* __restrict__ St, const unsigned short* __restrict__ Vwm,
    unsigned short* __restrict__ Tout, unsigned short* __restrict__ Vf) {
  int b   = blockIdx.x;
  int byr = blockIdx.y;
  int mode = (byr >= 64);
  int by  = mode ? byr - 64 : byr;
  int w   = threadIdx.x >> 6;
  int c0  = blockIdx.z*64;
  int lane = threadIdx.x & 63;
  int lo = lane & 15, hi = lane >> 4;
  const unsigned short* Bm = mode ? Vwm : St;
  __shared__ unsigned short lsh[64][72];
  floatx4 acc[4] = {};
  const unsigned short* kft = Kf + (size_t)(b*NTIL + by)*16384 + lane*8;
#pragma unroll
  for (int k = 0; k < 8; ++k) {
    short8 af = ld8(kft + (k*4 + w)*512);
#pragma unroll
    for (int t = 0; t < 4; ++t) {
      short8 bf = ld8(Bm + (size_t)(c0 + t*16 + lo)*CC + k*32 + hi*8);
      acc[t] = __builtin_amdgcn_mfma_f32_16x16x32_bf16(af, bf, acc[t], 0, 0, 0);
    }
  }
  if (!mode) {
#pragma unroll
    for (int t = 0; t < 4; ++t)
#pragma unroll
      for (int r = 0; r < 4; ++r)
        lsh[w*16 + hi*4 + r][t*16 + lo] = f2b(acc[t][r]);
    __syncthreads();
    int tid = threadIdx.x;
    int nl = tid >> 2, seg = tid & 3;
    unsigned short* dst = Tout + ((size_t)b*HWS + by*64 + nl)*CC + c0 + seg*16;
    st8(dst,     ld8(&lsh[nl][seg*16]));
    st8(dst + 8, ld8(&lsh[nl][seg*16 + 8]));
  } else {
#pragma unroll
    for (int t = 0; t < 4; ++t)
#pragma unroll
      for (int r = 0; r < 4; ++r)
        lsh[t*16 + lo][w*16 + hi*4 + r] = f2b(acc[t][r]);
    __syncthreads();
    unsigned short* vfb2 = Vf + (size_t)(b*NTIL + by)*16384;
#pragma unroll
    for (int ss = 0; ss < 2; ++ss) {
      int idx = w*2 + ss;            // [0,8)
      int h = idx >> 2, t4 = idx & 3;
      int s = h*16 + (c0 >> 4) + t4;
      short8 v = ld8(&lsh[t4*16 + (lane & 15)][h*32 + (lane >> 4)*8]);
      st8(vfb2 + s*512 + lane*8, v);
    }
  }
}

// ---- score mimicry of np/BLAS fp32 T-path. v3: img tile stored TRANSPOSED
//      (Ut[c][nl], stride 36 floats = 144B, 16B-aligned) so the inner loop's
//      32 scalar LDS broadcasts become 8x ds_read_b128 broadcasts (4x fewer
//      LDS ops; was the LDS-port bottleneck at ~65k ops/CU). Each acc[nl]
//      chain keeps its sequential c-order -> scores bit-identical.
__global__ __launch_bounds__(256) void scores_kernel(const float* __restrict__ img,
    const float* __restrict__ sim, const float* __restrict__ exe,
    float* __restrict__ score32) {
  int b = blockIdx.x, n0 = blockIdx.y*32;
  int d = threadIdx.x;
  __shared__ float Ut[256][36];       // Ut[c][nl] = img[b, c, n0+nl]
  __shared__ float R[32][257];        // T32[nl][d]
  __shared__ float E[256];
  for (int idx = threadIdx.x; idx < 32*256; idx += 256) {
    int nl = idx & 31, c = idx >> 5;
    Ut[c][nl] = img[((size_t)b*CC + c)*HWS + n0 + nl];
  }
  E[d] = 1.2f * exe[b*CC + d];
  __syncthreads();
  float acc[32];
#pragma unroll
  for (int nl = 0; nl < 32; ++nl) acc[nl] = 0.f;
  for (int c = 0; c < CC; ++c) {
    float s_cd = sim[c*CC + d];
    const floatx4* up = (const floatx4*)&Ut[c][0];
#pragma unroll
    for (int j = 0; j < 8; ++j) {
      floatx4 u4 = up[j];
#pragma unroll
      for (int q = 0; q < 4; ++q)
        acc[j*4 + q] = fmaf(u4[q], s_cd, acc[j*4 + q]);
    }
  }
#pragma unroll
  for (int nl = 0; nl < 32; ++nl) R[nl][d] = acc[nl];
  __syncthreads();
  if (d < 32) {
    float s = 0.f;
    for (int dd = 0; dd < CC; ++dd) s = fmaf(R[d][dd], E[dd], s);
    score32[b*HWS + n0 + d] = s;
  }
}

// ---- top-150 via exact radix-select on distinct 44-bit keys + bitonic-256 sort.
__global__ __launch_bounds__(64) void select_kernel(const float* __restrict__ scores,
                                                    int* __restrict__ qids) {
  int b = blockIdx.x, lane = threadIdx.x;
  __shared__ float sc[HWS];
  __shared__ unsigned long long kx[HWS];
  __shared__ unsigned long long list[256];
  __shared__ unsigned int hist[256];
  __shared__ unsigned int st[4];
  __shared__ unsigned long long sh_base;

  const floatx4* s4 = (const floatx4*)(scores + (size_t)b*HWS);
  floatx4* c4 = (floatx4*)sc;
#pragma unroll
  for (int i = 0; i < 16; ++i) c4[i*64 + lane] = s4[i*64 + lane];
  __syncthreads();

  for (int i = 0; i < 64; ++i) {
    int idx = i*64 + lane;
    int y = i, x = lane;
    float c0 = sc[idx];
    float v = c0;
    if (y >= 1 && y <= 62 && x >= 1 && x <= 62) {
      bool ismax = (c0 > sc[idx-64]) && (c0 >= sc[idx+64]) &&
                   (c0 > sc[idx-1])  && (c0 >= sc[idx+1]);
      if (!ismax) v = c0 - 1e9f;
    }
    unsigned u = __float_as_uint(v);
    u = (u & 0x80000000u) ? ~u : (u | 0x80000000u);
    kx[idx] = (((unsigned long long)u) << 12) | (unsigned long long)(4095 - idx);
  }
  __syncthreads();

  unsigned long long base = 0;
  unsigned int need = 150, C = 0;
  for (int s = 36; s >= 4; s -= 8) {
    for (int i = lane; i < 256; i += 64) hist[i] = 0;
    __syncthreads();
    unsigned long long pref = base >> (s + 8);
    for (int i = 0; i < 64; ++i) {
      unsigned long long k = kx[i*64 + lane];
      if ((k >> (s + 8)) == pref) atomicAdd(&hist[(unsigned)(k >> s) & 255u], 1u);
    }
    __syncthreads();
    if (lane == 0) {
      unsigned cum = 0; int B = 0;
      for (int bin = 255; bin >= 0; --bin) {
        cum += hist[bin];
        if (cum >= need) { B = bin; break; }
      }
      st[0] = (150u - need) + cum;
      st[1] = need - (cum - hist[B]);
      sh_base = base | ((unsigned long long)B << s);
    }
    __syncthreads();
    C = st[0]; need = st[1]; base = sh_base;
    if (C <= 256u) break;
  }

  if (lane == 0) st[2] = 0;
  __syncthreads();
  for (int i = 0; i < 64; ++i) {
    unsigned long long k = kx[i*64 + lane];
    if (k >= base) {
      unsigned p = atomicAdd(&st[2], 1u);
      list[p] = k;
    }
  }
  __syncthreads();
  for (int i = lane; i < 256; i += 64) if (i >= (int)C) list[i] = 0ull;
  __syncthreads();

  for (int kk = 2; kk <= 256; kk <<= 1) {
    for (int j = kk >> 1; j > 0; j >>= 1) {
#pragma unroll
      for (int tt = 0; tt < 2; ++tt) {
        int t = lane + tt*64;
        int i2 = ((t & ~(j - 1)) << 1) | (t & (j - 1));
        int p2 = i2 | j;
        bool desc = ((i2 & kk) == 0);
        unsigned long long a = list[i2], c = list[p2];
        bool sw = desc ? (a < c) : (a > c);
        if (sw) { list[i2] = c; list[p2] = a; }
      }
      __syncthreads();
    }
  }

  for (int q = lane; q < 150; q += 64)
    qids[b*150 + q] = 4095 - (int)(list[q] & 0xFFFull);
}

// ---- fused flash attention v9 (FROZEN schedule, proven 116us x6). Prologue
//      reads diag/exe rows from Kf (bit-identical bytes, wave-contiguous).
__global__ __launch_bounds__(256, 1) void flash_kernel(
    const unsigned short* __restrict__ Tb, const unsigned short* __restrict__ Kf,
    const unsigned short* __restrict__ Vf, const float* __restrict__ mask,
    const float* __restrict__ colb,
    float* __restrict__ acc0, float* __restrict__ accH, float* __restrict__ lsums) {
  int blk = blockIdx.x;                       // 256 blocks
  int b    = (blk & 7) >> 1;                  // batch pinned to XCD pair
  int half = blk & 1;                         // KV half pinned to XCD
  int g    = blk >> 3;                        // row-group-128 [0,32)
  int tid = threadIdx.x;
  int wave = tid >> 6, lane = tid & 63;
  int lo = lane & 15, hi = lane >> 4;
  int n0 = g*128 + wave*32;                   // this wave's 32 Q-rows
  int t0 = half ? 33 : 0, t1 = half ? NTIL : 33;

  __shared__ unsigned short pbuf[4][1152];    // per-wave P / M-exchange
  unsigned short* plw = &pbuf[wave][0];

  // Q fragments for this wave's two row-groups
  short8 q0[8], q1[8];
  const unsigned short* tb0 = Tb + ((size_t)b*HWS + n0 + lo)*CC + hi*8;
#pragma unroll
  for (int k = 0; k < 8; ++k) { q0[k] = ld8(tb0 + k*32); q1[k] = ld8(tb0 + 16*CC + k*32); }

  const unsigned short* kfb = Kf + (size_t)b*NTIL*16384 + lane*8;
  const unsigned short* vfb = Vf + (size_t)b*NTIL*16384 + lane*8;

  // prologue staging: kaA(t0) -> X, kaB(t0) -> Y (overlaps prologue dots)
  short8 X[16], Y[16];
#pragma unroll
  for (int i = 0; i < 16; ++i) X[i] = ld8(kfb + (size_t)t0*16384 + i*512);
#pragma unroll
  for (int i = 0; i < 16; ++i) Y[i] = ld8(kfb + (size_t)t0*16384 + (16 + i)*512);

  const float* mk = mask + b*HWS;

  // ---- prologue: diag and exe dots (fp32), fixed row max M = pick + 2
  float crb0[4], Msub0[4], crb1[4], Msub1[4];
  {
    int nt  = n0 >> 6;                        // 64-row tile of this wave's rows
    int t16 = (n0 & 63) >> 4;                 // 16-row group within tile
    const unsigned short* kfd = Kf + (size_t)(b*NTIL + nt)*16384 + lane*8;
    const unsigned short* kfe = Kf + (size_t)(b*NTIL + 64)*16384 + hi*128;
    // row-group 0
    float ddot = 0.f, edot = 0.f;
#pragma unroll
    for (int k = 0; k < 8; ++k) {
      short8 kd = ld8(kfd + (k*4 + t16)*512);
      short8 ke = ld8(kfe + (k*4)*512);
#pragma unroll
      for (int j = 0; j < 8; ++j) {
        float qf = b2f((unsigned short)q0[k][j]);
        ddot = fmaf(qf, b2f((unsigned short)kd[j]), ddot);
        edot = fmaf(qf, b2f((unsigned short)ke[j]), edot);
      }
    }
    ddot += __shfl_xor(ddot, 16); ddot += __shfl_xor(ddot, 32);
    edot += __shfl_xor(edot, 16); edot += __shfl_xor(edot, 32);
    float Mrow = ((mk[n0 + lo] == 1.0f) ? ddot : edot) + 2.0f;
    float* fM = (float*)plw;
    fM[lo] = Mrow;
#pragma unroll
    for (int r = 0; r < 4; ++r) {
      Msub0[r] = fM[hi*4 + r];
      crb0[r]  = (mk[n0 + hi*4 + r] - 1.0f)*1e9f - Msub0[r];
    }
    // row-group 1
    ddot = 0.f; edot = 0.f;
#pragma unroll
    for (int k = 0; k < 8; ++k) {
      short8 kd = ld8(kfd + (k*4 + t16 + 1)*512);
      short8 ke = ld8(kfe + (k*4)*512);
#pragma unroll
      for (int j = 0; j < 8; ++j) {
        float qf = b2f((unsigned short)q1[k][j]);
        ddot = fmaf(qf, b2f((unsigned short)kd[j]), ddot);
        edot = fmaf(qf, b2f((unsigned short)ke[j]), edot);
      }
    }
    ddot += __shfl_xor(ddot, 16); ddot += __shfl_xor(ddot, 32);
    edot += __shfl_xor(edot, 16); edot += __shfl_xor(edot, 32);
    float Mrow1 = ((mk[n0 + 16 + lo] == 1.0f) ? ddot : edot) + 2.0f;
    fM[lo] = Mrow1;
#pragma unroll
    for (int r = 0; r < 4; ++r) {
      Msub1[r] = fM[hi*4 + r];
      crb1[r]  = (mk[n0 + 16 + hi*4 + r] - 1.0f)*1e9f - Msub1[r];
    }
  }

  float lsum0[4] = {0.f, 0.f, 0.f, 0.f};
  float lsum1[4] = {0.f, 0.f, 0.f, 0.f};
  floatx4 o0[16] = {};
  floatx4 o1[16] = {};
  const float* cbb = colb + b*MPAD;

  for (int mt = t0; mt < t1; ++mt) {
    int m0 = mt*64;
    const unsigned short* vs = vfb + (size_t)mt*16384;
    // ---- QK-A: K slots 0..15 (k=0..3) from X; each fragment feeds both groups
    floatx4 s0[4] = {}, s1[4] = {};
#pragma unroll
    for (int k = 0; k < 4; ++k)
#pragma unroll
      for (int t = 0; t < 4; ++t) {
        s0[t] = __builtin_amdgcn_mfma_f32_16x16x32_bf16(q0[k], X[k*4 + t], s0[t], 0, 0, 0);
        s1[t] = __builtin_amdgcn_mfma_f32_16x16x32_bf16(q1[k], X[k*4 + t], s1[t], 0, 0, 0);
      }
    // issue vaA(mt) -> X (X dead after QK-A)
#pragma unroll
    for (int i = 0; i < 16; ++i) X[i] = ld8(vs + i*512);
    // ---- QK-B: K slots 16..31 (k=4..7) from Y
#pragma unroll
    for (int k = 4; k < 8; ++k)
#pragma unroll
      for (int t = 0; t < 4; ++t) {
        s0[t] = __builtin_amdgcn_mfma_f32_16x16x32_bf16(q0[k], Y[(k-4)*4 + t], s0[t], 0, 0, 0);
        s1[t] = __builtin_amdgcn_mfma_f32_16x16x32_bf16(q1[k], Y[(k-4)*4 + t], s1[t], 0, 0, 0);
      }
    // issue vaB(mt) -> Y (Y dead after QK-B)
#pragma unroll
    for (int i = 0; i < 16; ++i) Y[i] = ld8(vs + (16 + i)*512);
    // ---- fixed-max softmax: p = exp(s + colb[m] + rowb[r] - M_r)
    float cb[4];
#pragma unroll
    for (int t = 0; t < 4; ++t) cb[t] = cbb[m0 + t*16 + lo];
    short8 pf00, pf01, pf10, pf11;
    { // row-group 0
      float pr[4][4];
#pragma unroll
      for (int t = 0; t < 4; ++t)
#pragma unroll
        for (int r = 0; r < 4; ++r)
          pr[t][r] = s0[t][r] + cb[t] + crb0[r];
      if (mt == NTIL-1 && lo == 0) {
        // exe column (m==4096, t==0): never row-masked -> drop rowb
#pragma unroll
        for (int r = 0; r < 4; ++r) pr[0][r] = s0[0][r] - Msub0[r];
      }
#pragma unroll
      for (int t = 0; t < 4; ++t)
#pragma unroll
        for (int r = 0; r < 4; ++r) {
          float p = __expf(pr[t][r]);
          lsum0[r] += p;
          plw[(hi*4 + r)*72 + t*16 + lo] = f2b(p);
        }
      pf00 = *(const short8*)&plw[lo*72 + hi*8];
      pf01 = *(const short8*)&plw[lo*72 + 32 + hi*8];
    }
    { // row-group 1
      float pr[4][4];
#pragma unroll
      for (int t = 0; t < 4; ++t)
#pragma unroll
        for (int r = 0; r < 4; ++r)
          pr[t][r] = s1[t][r] + cb[t] + crb1[r];
      if (mt == NTIL-1 && lo == 0) {
#pragma unroll
        for (int r = 0; r < 4; ++r) pr[0][r] = s1[0][r] - Msub1[r];
      }
#pragma unroll
      for (int t = 0; t < 4; ++t)
#pragma unroll
        for (int r = 0; r < 4; ++r) {
          float p = __expf(pr[t][r]);
          lsum1[r] += p;
          plw[(hi*4 + r)*72 + t*16 + lo] = f2b(p);
        }
      pf10 = *(const short8*)&plw[lo*72 + hi*8];
      pf11 = *(const short8*)&plw[lo*72 + 32 + hi*8];
    }
    // ---- PV-A: V slots 0..15 (m 0..31) from X
#pragma unroll
    for (int sl = 0; sl < 16; ++sl) {
      o0[sl] = __builtin_amdgcn_mfma_f32_16x16x32_bf16(pf00, X[sl], o0[sl], 0, 0, 0);
      o1[sl] = __builtin_amdgcn_mfma_f32_16x16x32_bf16(pf10, X[sl], o1[sl], 0, 0, 0);
    }
    // issue kaA(mt+1) -> X
    if (mt + 1 < t1) {
      const unsigned short* ks = kfb + (size_t)(mt+1)*16384;
#pragma unroll
      for (int i = 0; i < 16; ++i) X[i] = ld8(ks + i*512);
    }
    // ---- PV-B: V slots 16..31 (m 32..63) from Y
#pragma unroll
    for (int sl = 0; sl < 16; ++sl) {
      o0[sl] = __builtin_amdgcn_mfma_f32_16x16x32_bf16(pf01, Y[sl], o0[sl], 0, 0, 0);
      o1[sl] = __builtin_amdgcn_mfma_f32_16x16x32_bf16(pf11, Y[sl], o1[sl], 0, 0, 0);
    }
    // issue kaB(mt+1) -> Y
    if (mt + 1 < t1) {
      const unsigned short* ks = kfb + (size_t)(mt+1)*16384;
#pragma unroll
      for (int i = 0; i < 16; ++i) Y[i] = ld8(ks + (16 + i)*512);
    }
  }
  // ---- l reduction over the 16 lo lanes (both groups)
#pragma unroll
  for (int r = 0; r < 4; ++r) {
#pragma unroll
    for (int off = 1; off < 16; off <<= 1) {
      lsum0[r] += __shfl_xor(lsum0[r], off);
      lsum1[r] += __shfl_xor(lsum1[r], off);
    }
  }
  // ---- epilogue: scatter fp32 UNNORMALIZED partials (no rounding here)
  float* op = (half ? accH : acc0) + (size_t)b*CC*HWS;
#pragma unroll
  for (int t = 0; t < 16; ++t)
#pragma unroll
    for (int r = 0; r < 4; ++r) {
      op[(size_t)(t*16 + lo)*HWS + n0 + hi*4 + r]      = o0[t][r];
      op[(size_t)(t*16 + lo)*HWS + n0 + 16 + hi*4 + r] = o1[t][r];
    }
  if (lo == 0) {
    float* lp = lsums + ((size_t)(half*NB + b))*HWS;
#pragma unroll
    for (int r = 0; r < 4; ++r) {
      lp[n0 + hi*4 + r]      = lsum0[r];
      lp[n0 + 16 + hi*4 + r] = lsum1[r];
    }
  }
}

// ---- merged finalize + gather (disjoint outputs; both ordered after
//      flash and select). blk < NB*CC: finalize; else gather.
__global__ __launch_bounds__(256) void fin_gather(const float* __restrict__ accH,
    const float* __restrict__ lsums, const float* __restrict__ img,
    const float* __restrict__ vw, const int* __restrict__ qids,
    float* __restrict__ out0, float* __restrict__ out1) {
  int blk = blockIdx.x;
  if (blk < NB*CC) {
    int b = blk >> 8;
    int d = blk & 255;
    size_t base = ((size_t)b*CC + d)*HWS;
    const float* l0 = lsums + (size_t)b*HWS;
    const float* l1 = lsums + (size_t)(NB + b)*HWS;
    for (int n = threadIdx.x; n < HWS; n += 256) {
      float inv = 1.0f / (l0[n] + l1[n]);
      float o = (out0[base + n] + accH[base + n]) * inv;
      out0[base + n] = b2f(f2b(o)) + img[base + n];
    }
    return;
  }
  int gb = blk - NB*CC;
  int b = gb / 150, q = gb % 150;
  int dd = threadIdx.x;
  __shared__ float col[CC];
  int id = qids[b*150 + q];
  col[dd] = img[((size_t)b*CC + dd)*HWS + id];
  __syncthreads();
  const float* vr = vw + dd*CC;
  float acc = 0.f;
  for (int c = 0; c < CC; ++c) acc = fmaf(col[c], vr[c], acc);
  out1[((size_t)(b*150 + q))*CC + dd] = acc;
}

extern "C" void kernel_launch(void* const* d_in, const int* in_sizes, int n_in,
                              void* d_out, int out_size, void* d_ws, size_t ws_size,
                              hipStream_t stream) {
  const float* img  = (const float*)d_in[0];
  const float* exe  = (const float*)d_in[1];
  const float* mask = (const float*)d_in[2];
  const float* sim  = (const float*)d_in[3];
  const float* vw   = (const float*)d_in[4];
  float* out0 = (float*)d_out;
  float* out1 = out0 + (size_t)NB*CC*HWS;

  char* ws = (char*)d_ws;
  size_t o = 0;
  unsigned short* Tb  = (unsigned short*)(ws + o); o += (size_t)NB*HWS*CC*2;
  unsigned short* Kf  = (unsigned short*)(ws + o); o += (size_t)NB*NTIL*16384*2;
  unsigned short* Vf  = (unsigned short*)(ws + o); o += (size_t)NB*NTIL*16384*2;
  unsigned short* St  = (unsigned short*)(ws + o); o += (size_t)CC*CC*2;
  unsigned short* Vw  = (unsigned short*)(ws + o); o += (size_t)CC*CC*2;
  float*          scores = (float*)(ws + o);       o += (size_t)NB*HWS*4;
  float*          colb   = (float*)(ws + o);       o += (size_t)NB*MPAD*4;
  int*            qids   = (int*)(ws + o);         o += (size_t)NB*150*4;
  float*          accH   = (float*)(ws + o);       o += (size_t)NB*CC*HWS*4;
  float*          lsums  = (float*)(ws + o);       o += (size_t)2*NB*HWS*4;

  build_kt   <<<dim3(NB+1, 65, 4), dim3(256), 0, stream>>>(img, exe, sim, vw, mask,
                                                           Kf, St, Vw, colb);
  gemm_small <<<dim3(NB, 129, 4),  dim3(256), 0, stream>>>(Kf, St, Vw, Tb, Vf);
  scores_kernel<<<dim3(NB, 128),   dim3(256), 0, stream>>>(img, sim, exe, scores);
  select_kernel<<<dim3(NB),        dim3(64),  0, stream>>>(scores, qids);
  flash_kernel <<<dim3(256),       dim3(256), 0, stream>>>(Tb, Kf, Vf, mask, colb,
                                                           out0, accH, lsums);
  fin_gather   <<<dim3(NB*CC + NB*150), dim3(256), 0, stream>>>(accH, lsums, img, vw,
                                                                qids, out0, out1);
}